// Round 10
// baseline (2533.023 us; speedup 1.0000x reference)
//
#include <hip/hip_runtime.h>
#include <cmath>
#include <cstdint>

typedef unsigned int u32;
typedef unsigned long long u64;
typedef float v2f __attribute__((ext_vector_type(2)));

#define A_TOT   159882
#define PRE_NMS 4000
#define POST_NMS 1000
#define NWORDS  63            // ceil(4000/64)
#define HIST_BINS 131072
#define HIST2_BINS 32768
#define SURV_CAP 8192
#define MONO_NEG_INF 0x007FFFFFu

struct BaseTab { float v[60]; };   // [level][aspect][4]

__device__ inline u32 mono32f(float s) {
    u32 u = __float_as_uint(s);
    return (u & 0x80000000u) ? ~u : (u | 0x80000000u);
}

// XLA:CPU / cephes vectorized expf (verified passing in r6 — DO NOT TOUCH)
__device__ inline float pexp_f(float x0) {
    float x = fminf(x0, 88.3762626647950f);
    x = fmaxf(x, -88.3762626647949f);
    float m = floorf(__builtin_fmaf(x, 1.44269504088896341f, 0.5f));
    float r = __builtin_fmaf(m, -0.693359375f, x);
    r = __builtin_fmaf(m, 2.12194440e-4f, r);
    float z = r * r;
    float y = 1.9875691500E-4f;
    y = __builtin_fmaf(y, r, 1.3981999507E-3f);
    y = __builtin_fmaf(y, r, 8.3334519073E-3f);
    y = __builtin_fmaf(y, r, 4.1665795894E-2f);
    y = __builtin_fmaf(y, r, 1.6666665459E-1f);
    y = __builtin_fmaf(y, r, 5.0000001201E-1f);
    y = __builtin_fmaf(y, z, r);
    y = y + 1.0f;
    return ldexpf(y, (int)m);
}

// verified decode chain (r6) — no fma, op order preserved
__device__ inline float4 decode_box(const float* __restrict__ reg,
                                    const float* __restrict__ anc,
                                    u32 i, bool* valid) {
#pragma clang fp contract(off)
    float x1 = anc[4 * i], y1 = anc[4 * i + 1], x2 = anc[4 * i + 2], y2 = anc[4 * i + 3];
    float acx = (x2 + x1) / 2.0f, acy = (y2 + y1) / 2.0f;
    float aw = x2 - x1, ah = y2 - y1;
    float t0 = reg[4 * i], t1 = reg[4 * i + 1], t2 = reg[4 * i + 2], t3 = reg[4 * i + 3];
    float cx = (t0 * aw) + acx;
    float cy = (t1 * ah) + acy;
    float w  = pexp_f(t2) * aw;
    float hh = pexp_f(t3) * ah;
    float bx1 = fminf(fmaxf(cx - w / 2.0f, 0.f), 1.f);
    float by1 = fminf(fmaxf(cy - hh / 2.0f, 0.f), 1.f);
    float bx2 = fminf(fmaxf(cx + w / 2.0f, 0.f), 1.f);
    float by2 = fminf(fmaxf(cy + hh / 2.0f, 0.f), 1.f);
    float wsz = bx2 - bx1, hsz = by2 - by1;
    *valid = (hsz >= 0.01f) && (wsz >= 0.01f);
    return make_float4(bx1, by1, bx2, by2);
}

// ---------------------------------------------------------------- packed-f32 helpers
// Single-instruction asm: per-lane IEEE f32 mul/add, identical rounding to the
// scalar chain (NO fma). op_sel broadcasts the selected word of src1.
__device__ inline v2f pk_mul_blo(v2f a, v2f b) {
    v2f d;
    asm("v_pk_mul_f32 %0, %1, %2 op_sel:[0,0] op_sel_hi:[1,0]"
        : "=v"(d) : "v"(a), "v"(b));
    return d;
}
__device__ inline v2f pk_mul_bhi(v2f a, v2f b) {
    v2f d;
    asm("v_pk_mul_f32 %0, %1, %2 op_sel:[0,1] op_sel_hi:[1,1]"
        : "=v"(d) : "v"(a), "v"(b));
    return d;
}
__device__ inline v2f pk_add(v2f a, v2f b) {
    v2f d;
    asm("v_pk_add_f32 %0, %1, %2" : "=v"(d) : "v"(a), "v"(b));
    return d;
}

// async global->LDS, 16B per lane; dest = wave-uniform base + lane*16
__device__ inline void gload16(const float* g, void* lds) {
    __builtin_amdgcn_global_load_lds(
        (const __attribute__((address_space(1))) void*)g,
        (__attribute__((address_space(3))) void*)lds,
        16, 0, 0);
}

// ---------------------------------------------------------------- W transpose + zero histograms (replaces 3 memsets)
__global__ __launch_bounds__(256) void wt_k(const float* __restrict__ w,
                                            float* __restrict__ Wt,
                                            u32* __restrict__ hist,
                                            u32* __restrict__ hist2,
                                            u32* __restrict__ counters) {
    int i = blockIdx.x * 256 + threadIdx.x;
    if (i < HIST_BINS) hist[i] = 0;
    if (i < HIST2_BINS) hist2[i] = 0;
    if (i < 64) counters[i] = 0;
    if (i >= 2304 * 256) return;
    int co = i & 255, knew = i >> 8;
    int g = knew >> 8;          // ky*3+kx
    int c = knew & 255;
    Wt[knew * 256 + co] = w[co * 2304 + c * 9 + g];
}

// ---------------------------------------------------------------- fused conv3x3 (all 5 levels, cout-split CS=2)
// Bit-exact Eigen chain: per element, k=(ky,kx,c) ascending, mul/add separate,
// kc=288 panel partials combined left-assoc. LINEAR-POSITION tiling: each block
// covers 32 consecutive flattened positions (zero x-padding). DOUBLE-BUFFERED
// LDS (W 2x16KB via global_load_lds, X 2x4KB via reg prefetch), one barrier
// per step. r10: x read as two ds_read_b64 (v2f) directly into the pk asm
// operands — no float4 subvector-extraction movs; kk unroll 8.
struct ConvMap {
    const float* feat[5];
    float* part[5];
    const float* Wt;
    const float* bias;
    u64 M[5];                 // magic: floor(x/gw) = (x*M)>>48 for x<2^17
    int bstart[6];
    int st[5], gh[5], gw[5], S[5], npan[5], fuse[5];
};

__global__ __launch_bounds__(256, 4) void conv_all(ConvMap cm)
{
#pragma clang fp contract(off)
    __shared__ float Ws[2][32][128];   // 32 KB
    __shared__ float Xs[2][32][32];    // 8 KB
    const int t  = threadIdx.x;
    const int cg = t & 31, xg = t >> 5;
    const int bid = blockIdx.x;
    const int l = (bid >= cm.bstart[1]) + (bid >= cm.bstart[2]) +
                  (bid >= cm.bstart[3]) + (bid >= cm.bstart[4]);
    const int local = bid - cm.bstart[l];
    const int st = cm.st[l], gh = cm.gh[l], gw = cm.gw[l];
    const int S = cm.S[l], npan = cm.npan[l];
    const float* __restrict__ feat = cm.feat[l];
    const float* __restrict__ Wt   = cm.Wt;
    float* __restrict__ part = cm.part[l];
    const int tile = local % st;
    const int zc   = local / st;
    const int s0   = tile * 32;
    const int z2 = zc & 1, pslot = zc >> 1;
    const int pb   = pslot * npan;
    const int send = (pb + npan) * 9;

    // per-lane (yq, xq) for staged column cg  (bit-identical padding decode)
    const u32 y00 = (u32)(((u64)(u32)s0 * cm.M[l]) >> 48);
    const int x00 = s0 - (int)y00 * gw;
    int xq = x00 + cg;
    int yq = (int)y00;
#pragma unroll
    for (int r = 0; r < 3; ++r) { if (xq >= gw) { xq -= gw; ++yq; } }

    const int srow0 = t >> 5;            // 0..7; rows srow0 + 8i
    const int wcol  = (t & 31) << 2;     // float col within 128-wide cout half
    const int wvoff = (t >> 6) * 1024;   // wave's byte chunk in a W buffer

    float px0, px1, px2, px3;            // prefetched X (named, never spilled)

#define ISSUE_X(s_) do {                                                       \
        int g_  = (s_) >> 3, cb_ = ((s_) & 7) << 5;                            \
        int ky_ = g_ / 3, kx_ = g_ - ky_ * 3;                                  \
        int yy_ = yq + ky_ - 1;                                                \
        int xx_ = xq + kx_ - 1;                                                \
        bool ok_ = (yy_ >= 0) && (yy_ < gh) && (xx_ >= 0) && (xx_ < gw);       \
        int yyc_ = ok_ ? yy_ : 0;                                              \
        int xcc_ = ok_ ? xx_ : 0;                                              \
        const float* xsrc_ = feat + ((size_t)(cb_ + srow0) * gh + yyc_) * gw   \
                                  + xcc_;                                      \
        size_t xstr_ = (size_t)(8 * gh) * gw;                                  \
        float xa_ = xsrc_[0];                                                  \
        float xb_ = xsrc_[xstr_];                                              \
        float xc2_ = xsrc_[2 * xstr_];                                         \
        float xd_ = xsrc_[3 * xstr_];                                          \
        px0 = ok_ ? xa_ : 0.f;                                                 \
        px1 = ok_ ? xb_ : 0.f;                                                 \
        px2 = ok_ ? xc2_ : 0.f;                                                \
        px3 = ok_ ? xd_ : 0.f;                                                 \
    } while (0)

#define COMMIT_X(b_) do {                                                      \
        Xs[b_][srow0][cg]      = px0;                                          \
        Xs[b_][srow0 + 8][cg]  = px1;                                          \
        Xs[b_][srow0 + 16][cg] = px2;                                          \
        Xs[b_][srow0 + 24][cg] = px3;                                          \
    } while (0)

#define ISSUE_W(s_, b_) do {                                                   \
        int g_  = (s_) >> 3, cb_ = ((s_) & 7) << 5;                            \
        const float* wsrc_ = Wt + ((size_t)(g_ * 256 + cb_ + srow0) * 256)     \
                               + z2 * 128 + wcol;                              \
        char* ldsW_ = (char*)(&Ws[b_][0][0]) + wvoff;                          \
        gload16(wsrc_,        ldsW_);                                          \
        gload16(wsrc_ + 2048, ldsW_ + 4096);                                   \
        gload16(wsrc_ + 4096, ldsW_ + 8192);                                   \
        gload16(wsrc_ + 6144, ldsW_ + 12288);                                  \
    } while (0)

    v2f tA0=(v2f)0.f, tA1=(v2f)0.f, tA2=(v2f)0.f, tA3=(v2f)0.f;
    v2f tB0=(v2f)0.f, tB1=(v2f)0.f, tB2=(v2f)0.f, tB3=(v2f)0.f;

    // prologue: stage first step into buf0, prefetch X(next)
    const int sfirst = pb * 9;            // send - sfirst = npan*9 >= 9
    ISSUE_X(sfirst);
    COMMIT_X(0);
    ISSUE_W(sfirst, 0);
    ISSUE_X(sfirst + 1);
    __syncthreads();                      // implied vmcnt/lgkm drain: buf0 ready
    int cur = 0;

    for (int pi = pb; pi < pb + npan; ++pi) {
        v2f pA0=(v2f)0.f, pA1=(v2f)0.f, pA2=(v2f)0.f, pA3=(v2f)0.f;
        v2f pB0=(v2f)0.f, pB1=(v2f)0.f, pB2=(v2f)0.f, pB3=(v2f)0.f;
        for (int j = 0; j < 9; ++j) {
            int s = pi * 9 + j;
            int nxt = cur ^ 1;
            bool more = (s + 1 < send);   // wave-uniform
            if (more) {
                COMMIT_X(nxt);            // px(s+1) -> Xs[nxt]
                ISSUE_W(s + 1, nxt);      // async, lands under kk loop
                if (s + 2 < send) ISSUE_X(s + 2);   // flies under kk loop
            }
            const float* Wb = &Ws[cur][0][0];
            const float* Xb = &Xs[cur][0][0];
#pragma unroll 8
            for (int kk = 0; kk < 32; ++kk) {
                v2f xlo = *(const v2f*)(Xb + kk * 32 + xg * 4);       // ds_read_b64
                v2f xhi = *(const v2f*)(Xb + kk * 32 + xg * 4 + 2);   // ds_read_b64
                v2f wA = *(const v2f*)(Wb + kk * 128 + cg * 2);
                pA0 = pk_add(pA0, pk_mul_blo(wA, xlo));
                pA1 = pk_add(pA1, pk_mul_bhi(wA, xlo));
                pA2 = pk_add(pA2, pk_mul_blo(wA, xhi));
                pA3 = pk_add(pA3, pk_mul_bhi(wA, xhi));
                v2f wB = *(const v2f*)(Wb + kk * 128 + 64 + cg * 2);
                pB0 = pk_add(pB0, pk_mul_blo(wB, xlo));
                pB1 = pk_add(pB1, pk_mul_bhi(wB, xlo));
                pB2 = pk_add(pB2, pk_mul_blo(wB, xhi));
                pB3 = pk_add(pB3, pk_mul_bhi(wB, xhi));
            }
            if (more) {                   // end-of-step: all reads of cur done,
                __syncthreads();          // staged nxt (W via vmcnt, X via lgkm) visible
                cur = nxt;
            }
        }
        tA0 = pk_add(tA0, pA0); tA1 = pk_add(tA1, pA1);   // left-assoc panel combine
        tA2 = pk_add(tA2, pA2); tA3 = pk_add(tA3, pA3);
        tB0 = pk_add(tB0, pB0); tB1 = pk_add(tB1, pB1);
        tB2 = pk_add(tB2, pB2); tB3 = pk_add(tB3, pB3);
    }
#undef ISSUE_X
#undef COMMIT_X
#undef ISSUE_W
    const int c0 = z2 * 128 + cg * 2;
    if (cm.fuse[l]) {                      // bias+relu, finalize's exact op order
        const float* bias = cm.bias;
        float bA0 = bias[c0], bA1 = bias[c0 + 1];
        float bB0 = bias[c0 + 64], bB1 = bias[c0 + 65];
        tA0[0] = fmaxf(tA0[0] + bA0, 0.f); tA0[1] = fmaxf(tA0[1] + bA1, 0.f);
        tA1[0] = fmaxf(tA1[0] + bA0, 0.f); tA1[1] = fmaxf(tA1[1] + bA1, 0.f);
        tA2[0] = fmaxf(tA2[0] + bA0, 0.f); tA2[1] = fmaxf(tA2[1] + bA1, 0.f);
        tA3[0] = fmaxf(tA3[0] + bA0, 0.f); tA3[1] = fmaxf(tA3[1] + bA1, 0.f);
        tB0[0] = fmaxf(tB0[0] + bB0, 0.f); tB0[1] = fmaxf(tB0[1] + bB1, 0.f);
        tB1[0] = fmaxf(tB1[0] + bB0, 0.f); tB1[1] = fmaxf(tB1[1] + bB1, 0.f);
        tB2[0] = fmaxf(tB2[0] + bB0, 0.f); tB2[1] = fmaxf(tB2[1] + bB1, 0.f);
        tB3[0] = fmaxf(tB3[0] + bB0, 0.f); tB3[1] = fmaxf(tB3[1] + bB1, 0.f);
    }
    float* op = part + (size_t)pslot * 256 * S;
    {
        int sp = s0 + xg * 4;
        size_t rA0 = (size_t)c0 * S + sp;
        size_t rA1 = rA0 + S;
        if (sp + 0 < S) { op[rA0 + 0] = tA0[0]; op[rA1 + 0] = tA0[1]; }
        if (sp + 1 < S) { op[rA0 + 1] = tA1[0]; op[rA1 + 1] = tA1[1]; }
        if (sp + 2 < S) { op[rA0 + 2] = tA2[0]; op[rA1 + 2] = tA2[1]; }
        if (sp + 3 < S) { op[rA0 + 3] = tA3[0]; op[rA1 + 3] = tA3[1]; }
        size_t rB0 = rA0 + (size_t)64 * S;
        size_t rB1 = rB0 + S;
        if (sp + 0 < S) { op[rB0 + 0] = tB0[0]; op[rB1 + 0] = tB0[1]; }
        if (sp + 1 < S) { op[rB0 + 1] = tB1[0]; op[rB1 + 1] = tB1[1]; }
        if (sp + 2 < S) { op[rB0 + 2] = tB2[0]; op[rB1 + 2] = tB2[1]; }
        if (sp + 3 < S) { op[rB0 + 3] = tB3[0]; op[rB1 + 3] = tB3[1]; }
    }
}

// ---------------------------------------------------------------- fused 1x1 heads (+ inline finalize for npan=8 levels)
// For levels 2-4, v is recomputed with finalize's exact op order:
// ((p0+p1+...+p7) + bias, fmax 0) — identical bits.
struct HeadMap {
    const float* h[5];
    int S[5], abase[5], npan[5], bstart[6];
};

__global__ __launch_bounds__(256) void head_all(
    HeadMap hm, const float* __restrict__ wc,
    const float* __restrict__ bc, const float* __restrict__ wr,
    const float* __restrict__ br, const float* __restrict__ bias,
    float* __restrict__ cls_out, float* __restrict__ reg_out)
{
#pragma clang fp contract(off)
    int bid = blockIdx.x;
    int l = (bid >= hm.bstart[1]) + (bid >= hm.bstart[2]) +
            (bid >= hm.bstart[3]) + (bid >= hm.bstart[4]);
    int local = bid - hm.bstart[l];
    const float* __restrict__ h = hm.h[l];
    const int S = hm.S[l];
    const int abase = hm.abase[l];
    const int npan = hm.npan[l];
    int s = local * 256 + threadIdx.x;
    if (s >= S) return;
    float ac[6]  = {0.f};
    float ar[12] = {0.f};
    for (int c = 0; c < 256; ++c) {
        size_t i = (size_t)c * S + s;
        float v;
        if (npan == 1) {
            v = h[i];
        } else {
            float vv = h[i];
            for (int p = 1; p < 8; ++p)
                vv = vv + h[(size_t)p * 256 * S + i];   // strict panel order
            v = fmaxf(vv + bias[c], 0.f);
        }
#pragma unroll
        for (int ch = 0; ch < 6; ++ch) {
            float prod = wc[ch * 256 + c] * v;
            ac[ch] = ac[ch] + prod;
        }
#pragma unroll
        for (int ch = 0; ch < 12; ++ch) {
            float prod = wr[ch * 256 + c] * v;
            ar[ch] = ar[ch] + prod;
        }
    }
    long b2 = (long)abase + (long)s * 3;
#pragma unroll
    for (int a = 0; a < 3; ++a) {
#pragma unroll
        for (int c2 = 0; c2 < 2; ++c2)
            cls_out[(b2 + a) * 2 + c2] = ac[a * 2 + c2] + bc[a * 2 + c2];
#pragma unroll
        for (int d = 0; d < 4; ++d)
            reg_out[(b2 + a) * 4 + d] = ar[a * 4 + d] + br[a * 4 + d];
    }
}

// ---------------------------------------------------------------- f32 score + key + hist (+ anchors inline, bit-identical)
__global__ __launch_bounds__(256) void score_k(
    const float* __restrict__ cls, const float* __restrict__ reg,
    BaseTab bt, u64* __restrict__ keys, u32* __restrict__ hist,
    float* __restrict__ anc_out)
{
#pragma clang fp contract(off)
    int i = blockIdx.x * 256 + threadIdx.x;
    if (i >= A_TOT) return;
    // ---- anchor (same expressions as the old anchors_k)
    int l, base, gw, str;
    if (i < 120000)      { l = 0; base = 0;      gw = 200; str = 4;  }
    else if (i < 150000) { l = 1; base = 120000; gw = 100; str = 8;  }
    else if (i < 157500) { l = 2; base = 150000; gw = 50;  str = 16; }
    else if (i < 159375) { l = 3; base = 157500; gw = 25;  str = 32; }
    else                 { l = 4; base = 159375; gw = 13;  str = 61; }
    int j = i - base;
    int sj = j / 3;
    int a = j - sj * 3;
    int yy = sj / gw;
    int xx = sj - yy * gw;
    float sx = (float)(xx * str), sy = (float)(yy * str);
    const float* bb = &bt.v[(l * 3 + a) * 4];
    float a0 = (sx + bb[0]) / 800.0f;
    float a1 = (sy + bb[1]) / 800.0f;
    float a2 = (sx + bb[2]) / 800.0f;
    float a3 = (sy + bb[3]) / 800.0f;
    anc_out[4 * i + 0] = a0;
    anc_out[4 * i + 1] = a1;
    anc_out[4 * i + 2] = a2;
    anc_out[4 * i + 3] = a3;
    // ---- softmax score
    float l0 = cls[2 * i], l1 = cls[2 * i + 1];
    float m  = fmaxf(l0, l1);
    float e0 = pexp_f(l0 - m);
    float e1 = pexp_f(l1 - m);
    float sum = e0 + e1;
    float sc  = e1 / sum;
    // ---- validity (decode chain, same op order; only valid used)
    float acx = (a2 + a0) / 2.0f, acy = (a3 + a1) / 2.0f;
    float aw = a2 - a0, ah = a3 - a1;
    float t0 = reg[4 * i], t1 = reg[4 * i + 1], t2 = reg[4 * i + 2], t3 = reg[4 * i + 3];
    float cx = (t0 * aw) + acx;
    float cy = (t1 * ah) + acy;
    float w  = pexp_f(t2) * aw;
    float hh = pexp_f(t3) * ah;
    float bx1 = fminf(fmaxf(cx - w / 2.0f, 0.f), 1.f);
    float by1 = fminf(fmaxf(cy - hh / 2.0f, 0.f), 1.f);
    float bx2 = fminf(fmaxf(cx + w / 2.0f, 0.f), 1.f);
    float by2 = fminf(fmaxf(cy + hh / 2.0f, 0.f), 1.f);
    float wsz = bx2 - bx1, hsz = by2 - by1;
    bool valid = (hsz >= 0.01f) && (wsz >= 0.01f);

    float score = valid ? sc : -INFINITY;
    u32 u = mono32f(score);
    keys[i] = ((u64)u << 32) | (u32)(~(u32)i);   // desc score, asc index
    atomicAdd(&hist[u >> 15], 1u);
}

// ---------------------------------------------------------------- coarse threshold bin
__global__ __launch_bounds__(1024) void topk_thresh(const u32* __restrict__ hist,
                                                    u32* __restrict__ counters) {
    __shared__ u32 part[1024];
    int t = threadIdx.x;
    u32 s = 0;
    for (int q = 0; q < 128; ++q) s += hist[HIST_BINS - 1 - (t * 128 + q)];
    part[t] = s;
    __syncthreads();
    if (t == 0) {
        u32 cum = 0, cumBefore = 0;
        int tc = 1023;
        for (int c = 0; c < 1024; ++c) {
            if (cum + part[c] >= PRE_NMS) { tc = c; cumBefore = cum; break; }
            cum += part[c];
        }
        u32 cum2 = cumBefore;
        int bstar = 0;
        for (int q = 0; q < 128; ++q) {
            int b = HIST_BINS - 1 - (tc * 128 + q);
            u32 hv = hist[b];
            if (cum2 + hv >= PRE_NMS) { bstar = b; break; }
            cum2 += hv;
        }
        counters[0] = (u32)bstar;
        counters[1] = cum2;
    }
}

// ---------------------------------------------------------------- fine histogram in bstar bin
__global__ __launch_bounds__(256) void hist2_k(const u64* __restrict__ keys,
                                               const u32* __restrict__ counters,
                                               u32* __restrict__ hist2) {
    int i = blockIdx.x * 256 + threadIdx.x;
    if (i >= A_TOT) return;
    u32 u = (u32)(keys[i] >> 32);
    if ((u >> 15) == counters[0]) atomicAdd(&hist2[u & 0x7FFF], 1u);
}

// ---------------------------------------------------------------- exact 32-bit cutoff
__global__ __launch_bounds__(1024) void thresh2_k(const u32* __restrict__ hist2,
                                                  u32* __restrict__ counters) {
    __shared__ u32 part[1024];
    int t = threadIdx.x;
    u32 s = 0;
    for (int q = 0; q < 32; ++q) s += hist2[HIST2_BINS - 1 - (t * 32 + q)];
    part[t] = s;
    __syncthreads();
    if (t == 0) {
        u32 bstar = counters[0];
        u32 cum = counters[1];
        int tc = 1023;
        u32 cumBefore = cum;
        for (int c = 0; c < 1024; ++c) {
            if (cum + part[c] >= PRE_NMS) { tc = c; cumBefore = cum; break; }
            cum += part[c];
        }
        u32 cum2 = cumBefore;
        u32 low = 0;
        for (int q = 0; q < 32; ++q) {
            int b = HIST2_BINS - 1 - (tc * 32 + q);
            u32 hv = hist2[b];
            if (cum2 + hv >= PRE_NMS) { low = (u32)b; break; }
            cum2 += hv;
        }
        counters[3] = (bstar << 15) | low;   // exact monotone-u cutoff
    }
}

// ---------------------------------------------------------------- compact survivors (exact)
__global__ __launch_bounds__(256) void compact_k(const u64* __restrict__ keys,
                                                 u32* __restrict__ counters,
                                                 u64* __restrict__ surv) {
    int i = blockIdx.x * 256 + threadIdx.x;
    if (i >= A_TOT) return;
    u32 cut = counters[3];
    u64 k = keys[i];
    if ((u32)(k >> 32) >= cut) {
        u32 slot = atomicAdd(&counters[2], 1u);
        if (slot < SURV_CAP) surv[slot] = k;
    }
}

// ---------------------------------------------------------------- bitonic sort + gather (recompute decode)
// Adaptive size: if n <= 4096 sort 4096 (78 passes) else 8192 (91). Zeros sort
// to the back either way; first PRE_NMS entries identical -> bit-exact.
__global__ __launch_bounds__(1024) void sort_topk(
    const u64* __restrict__ surv, const u32* __restrict__ counters,
    const float* __restrict__ reg, const float* __restrict__ anc,
    float* __restrict__ boxes4k, u64* __restrict__ finmask)
{
    __shared__ u64 K[SURV_CAP];   // 64 KB
    int t = threadIdx.x;
    u32 n = counters[2];
    if (n > SURV_CAP) n = SURV_CAP;
    const int msize = (n <= 4096) ? 4096 : SURV_CAP;
    for (int p = t; p < msize; p += 1024) K[p] = (p < (int)n) ? surv[p] : 0ull;
    __syncthreads();
    for (int k = 2; k <= msize; k <<= 1) {
        for (int j = k >> 1; j > 0; j >>= 1) {
            for (int p = t; p < msize / 2; p += 1024) {
                int i = 2 * p - (p & (j - 1));
                int pr = i + j;
                bool desc = ((i & k) == 0);
                u64 a = K[i], b = K[pr];
                if (desc ? (a < b) : (a > b)) { K[i] = b; K[pr] = a; }
            }
            __syncthreads();
        }
    }
    for (int jj = t; jj < PRE_NMS; jj += 1024) {
        u64 key = K[jj];
        u32 u = (u32)(key >> 32);
        float b0 = 0.f, b1 = 0.f, b2 = 0.f, b3 = 0.f;
        if (u > MONO_NEG_INF) {
            u32 idx = ~(u32)key;
            bool valid;
            float4 bx = decode_box(reg, anc, idx, &valid);
            b0 = bx.x; b1 = bx.y; b2 = bx.z; b3 = bx.w;
        }
        boxes4k[4 * jj + 0] = b0;
        boxes4k[4 * jj + 1] = b1;
        boxes4k[4 * jj + 2] = b2;
        boxes4k[4 * jj + 3] = b3;
    }
    if (t < NWORDS) {
        u64 wmask = 0;
        for (int b = 0; b < 64; ++b) {
            int jj = t * 64 + b;
            if (jj < PRE_NMS) {
                u32 u = (u32)(K[jj] >> 32);
                if (u > MONO_NEG_INF) wmask |= (1ull << b);
            }
        }
        finmask[t] = wmask;
    }
}

// ---------------------------------------------------------------- suppression matrix (f32, np op order)
__global__ __launch_bounds__(64) void supmat_k(const float* __restrict__ boxes4k,
                                               u64* __restrict__ sup) {
#pragma clang fp contract(off)
    __shared__ float cb[64][4];
    int rb = blockIdx.y, cbk = blockIdx.x;
    int tl = threadIdx.x;
    int j = cbk * 64 + tl;
    if (j < PRE_NMS) {
        cb[tl][0] = boxes4k[4 * j + 0];
        cb[tl][1] = boxes4k[4 * j + 1];
        cb[tl][2] = boxes4k[4 * j + 2];
        cb[tl][3] = boxes4k[4 * j + 3];
    } else {
        cb[tl][0] = cb[tl][1] = cb[tl][2] = cb[tl][3] = 0.f;
    }
    __syncthreads();
    int i = rb * 64 + tl;
    if (i >= PRE_NMS) return;
    float ax1 = boxes4k[4 * i + 0], ay1 = boxes4k[4 * i + 1];
    float ax2 = boxes4k[4 * i + 2], ay2 = boxes4k[4 * i + 3];
    float aarea = fmaxf(ax2 - ax1, 0.f) * fmaxf(ay2 - ay1, 0.f);
    u64 w = 0;
    for (int q = 0; q < 64; ++q) {
        int jg = cbk * 64 + q;
        if (jg >= PRE_NMS || jg <= i) continue;
        float bx1 = cb[q][0], by1 = cb[q][1], bx2 = cb[q][2], by2 = cb[q][3];
        float barea = fmaxf(bx2 - bx1, 0.f) * fmaxf(by2 - by1, 0.f);
        float lx = fmaxf(ax1, bx1), ly = fmaxf(ay1, by1);
        float rx = fminf(ax2, bx2), ry = fminf(ay2, by2);
        float iw = fmaxf(rx - lx, 0.f), ih = fmaxf(ry - ly, 0.f);
        float inter = iw * ih;
        float uni = (aarea + barea) - inter;
        float iou = (uni > 0.f) ? inter / uni : 0.f;
        if (iou > 0.7f) w |= (1ull << q);
    }
    sup[(size_t)i * NWORDS + cbk] = w;
}

// ---------------------------------------------------------------- sequential NMS scan + output (merged, depth-3 prefetch)
__device__ inline u64 shfl_u64(u64 v, int lane) {
    int lo = __shfl((int)(u32)(v & 0xFFFFFFFFull), lane, 64);
    int hi = __shfl((int)(u32)(v >> 32), lane, 64);
    return ((u64)(u32)hi << 32) | (u32)lo;
}

__global__ __launch_bounds__(256) void nms_out_k(const u64* __restrict__ sup,
                                                 const u64* __restrict__ finmask,
                                                 const float* __restrict__ boxes4k,
                                                 float* __restrict__ roi_out) {
    __shared__ u64 keepw_s[NWORDS];
    __shared__ u32 pref[NWORDS + 1];
    int t = threadIdx.x;
    if (t < 64) {
        int lane = t;
        u64 keep = (lane < NWORDS) ? finmask[lane] : 0ull;
        u64 cur[8], n1[8], n2[8], nw[8];
#define LDROW(dst_, i0_)                                                       \
        _Pragma("unroll")                                                      \
        for (int q = 0; q < 8; ++q) {                                          \
            int i_ = (i0_) + q;                                                \
            dst_[q] = (lane < NWORDS && i_ < PRE_NMS)                          \
                      ? sup[(size_t)i_ * NWORDS + lane] : 0ull;                \
        }
        LDROW(cur, 0)
        LDROW(n1, 8)
        LDROW(n2, 16)
        for (int base = 0; base < PRE_NMS; base += 8) {
            LDROW(nw, base + 24)          // 24 rows in flight over this body
#pragma unroll
            for (int q = 0; q < 8; ++q) {
                int i = base + q;
                int wi = i >> 6, bi = i & 63;
                u64 kw = shfl_u64(keep, wi);
                if ((kw >> bi) & 1ull) keep &= ~cur[q];
            }
#pragma unroll
            for (int q = 0; q < 8; ++q) { cur[q] = n1[q]; n1[q] = n2[q]; n2[q] = nw[q]; }
        }
#undef LDROW
        if (lane < NWORDS) keepw_s[lane] = keep;
    }
    __syncthreads();
    if (t == 0) {
        u32 run = 0;
        for (int w = 0; w < NWORDS; ++w) { pref[w] = run; run += (u32)__popcll(keepw_s[w]); }
        pref[NWORDS] = run;
    }
    __syncthreads();
    u32 total = pref[NWORDS];
    u32 nk = total < (u32)POST_NMS ? total : (u32)POST_NMS;
    for (int j = t; j < PRE_NMS; j += 256) {
        int wi = j >> 6, bi = j & 63;
        u64 kw = keepw_s[wi];
        if ((kw >> bi) & 1ull) {
            u32 rank = pref[wi] + (u32)__popcll(kw & ((1ull << bi) - 1ull));
            if (rank < (u32)POST_NMS) {
                roi_out[4 * rank + 0] = boxes4k[4 * j + 0];
                roi_out[4 * rank + 1] = boxes4k[4 * j + 1];
                roi_out[4 * rank + 2] = boxes4k[4 * j + 2];
                roi_out[4 * rank + 3] = boxes4k[4 * j + 3];
            }
        }
    }
    for (int r2 = t; r2 < POST_NMS; r2 += 256) {
        if ((u32)r2 >= nk) {
            roi_out[4 * r2 + 0] = 0.f;
            roi_out[4 * r2 + 1] = 0.f;
            roi_out[4 * r2 + 2] = 0.f;
            roi_out[4 * r2 + 3] = 0.f;
        }
    }
}

// ================================================================ host
extern "C" void kernel_launch(void* const* d_in, const int* in_sizes, int n_in,
                              void* d_out, int out_size, void* d_ws, size_t ws_size,
                              hipStream_t stream) {
    const float* feat[5] = {
        (const float*)d_in[1], (const float*)d_in[2], (const float*)d_in[3],
        (const float*)d_in[4], (const float*)d_in[5]};
    const float* w_inter = (const float*)d_in[6];
    const float* b_inter = (const float*)d_in[7];
    const float* w_cls   = (const float*)d_in[8];
    const float* b_cls   = (const float*)d_in[9];
    const float* w_reg   = (const float*)d_in[10];
    const float* b_reg   = (const float*)d_in[11];

    float* out     = (float*)d_out;
    float* out_cls = out;                       // 159882*2
    float* out_reg = out + 319764;              // 159882*4
    float* out_roi = out + 959292;              // 1000*4
    float* out_anc = out + 963292;              // 159882*4

    static const int GH[5]    = {200, 100, 50, 25, 13};
    static const int GW[5]    = {200, 100, 50, 25, 13};
    static const int SL[5]    = {40000, 10000, 2500, 625, 169};
    static const int ABASE[5] = {0, 120000, 150000, 157500, 159375};
    static const int NPAN_ST[5] = {1, 1, 8, 8, 8};   // panel-partial slots stored

    // ---- workspace carve (~85 MB total)
    char* p = (char*)d_ws;
    size_t off = 0;
    auto alloc = [&](size_t bytes) -> void* {
        void* r = p + off;
        off = (off + bytes + 255) & ~(size_t)255;
        return r;
    };
    float* Wt      = (float*)alloc((size_t)2304 * 256 * 4);
    float* part[5];
    for (int l = 0; l < 5; ++l)
        part[l] = (float*)alloc((size_t)NPAN_ST[l] * 256 * SL[l] * 4);
    u64*   keys    = (u64*)  alloc((size_t)A_TOT * 8);
    u32*   hist    = (u32*)  alloc((size_t)HIST_BINS * 4);
    u32*   hist2   = (u32*)  alloc((size_t)HIST2_BINS * 4);
    u32*   counters= (u32*)  alloc(256);
    u64*   surv    = (u64*)  alloc((size_t)SURV_CAP * 8);
    float* boxes4k = (float*)alloc((size_t)PRE_NMS * 4 * 4);
    u64*   finmask = (u64*)  alloc(64 * 8);
    u64*   supmat  = (u64*)  alloc((size_t)PRE_NMS * NWORDS * 8);
    (void)ws_size;

    // ---- host anchor base table, float32 to match np (round half-even)
    BaseTab bt;
    {
        const float sizes[5] = {32.f, 64.f, 128.f, 256.f, 512.f};
        const float asp[3] = {0.5f, 1.0f, 2.0f};
        for (int l = 0; l < 5; ++l)
            for (int a = 0; a < 3; ++a) {
                float hr = sqrtf(asp[a]);
                float wr = 1.0f / hr;
                float wsf = sizes[l] * wr;
                float hsf = sizes[l] * hr;
                bt.v[(l * 3 + a) * 4 + 0] = rintf(-wsf / 2.0f);
                bt.v[(l * 3 + a) * 4 + 1] = rintf(-hsf / 2.0f);
                bt.v[(l * 3 + a) * 4 + 2] = rintf( wsf / 2.0f);
                bt.v[(l * 3 + a) * 4 + 3] = rintf( hsf / 2.0f);
            }
    }

    wt_k<<<2304, 256, 0, stream>>>(w_inter, Wt, hist, hist2, counters);

    // ---- fused conv (all 5 levels, one launch, linear-position tiles)
    ConvMap cm;
    cm.Wt = Wt;
    cm.bias = b_inter;
    int bacc = 0;
    for (int l = 0; l < 5; ++l) {
        cm.feat[l] = feat[l];
        cm.part[l] = part[l];
        int st = (SL[l] + 31) / 32;
        cm.st[l] = st; cm.gh[l] = GH[l]; cm.gw[l] = GW[l]; cm.S[l] = SL[l];
        cm.M[l] = (((u64)1 << 48) + (u64)GW[l] - 1) / (u64)GW[l];
        int zsplit = NPAN_ST[l];
        cm.npan[l] = (zsplit == 1) ? 8 : 1;
        cm.fuse[l] = (zsplit == 1) ? 1 : 0;       // bias+relu fused for levels 0/1
        cm.bstart[l] = bacc;
        bacc += st * (zsplit * 2);
    }
    cm.bstart[5] = bacc;
    conv_all<<<bacc, 256, 0, stream>>>(cm);

    // ---- fused heads (finalize for levels 2-4 done inline)
    HeadMap hm;
    int hacc = 0;
    for (int l = 0; l < 5; ++l) {
        hm.h[l] = part[l];
        hm.S[l] = SL[l];
        hm.abase[l] = ABASE[l];
        hm.npan[l] = NPAN_ST[l];
        hm.bstart[l] = hacc;
        hacc += (SL[l] + 255) / 256;
    }
    hm.bstart[5] = hacc;
    head_all<<<hacc, 256, 0, stream>>>(hm, w_cls, b_cls, w_reg, b_reg,
                                       b_inter, out_cls, out_reg);

    int nbA = (A_TOT + 255) / 256;
    score_k<<<nbA, 256, 0, stream>>>(out_cls, out_reg, bt, keys, hist, out_anc);
    topk_thresh<<<1, 1024, 0, stream>>>(hist, counters);
    hist2_k<<<nbA, 256, 0, stream>>>(keys, counters, hist2);
    thresh2_k<<<1, 1024, 0, stream>>>(hist2, counters);
    compact_k<<<nbA, 256, 0, stream>>>(keys, counters, surv);
    sort_topk<<<1, 1024, 0, stream>>>(surv, counters, out_reg, out_anc, boxes4k, finmask);
    supmat_k<<<dim3(NWORDS, NWORDS), 64, 0, stream>>>(boxes4k, supmat);
    nms_out_k<<<1, 256, 0, stream>>>(supmat, finmask, boxes4k, out_roi);
}

// Round 11
// 2498.949 us; speedup vs baseline: 1.0136x; 1.0136x over previous
//
#include <hip/hip_runtime.h>
#include <cmath>
#include <cstdint>

typedef unsigned int u32;
typedef unsigned long long u64;
typedef float v2f __attribute__((ext_vector_type(2)));

#define A_TOT   159882
#define PRE_NMS 4000
#define POST_NMS 1000
#define NWORDS  63            // ceil(4000/64)
#define HIST_BINS 131072
#define HIST2_BINS 32768
#define SURV_CAP 8192
#define MONO_NEG_INF 0x007FFFFFu

struct BaseTab { float v[60]; };   // [level][aspect][4]

__device__ inline u32 mono32f(float s) {
    u32 u = __float_as_uint(s);
    return (u & 0x80000000u) ? ~u : (u | 0x80000000u);
}

// XLA:CPU / cephes vectorized expf (verified passing in r6 — DO NOT TOUCH)
__device__ inline float pexp_f(float x0) {
    float x = fminf(x0, 88.3762626647950f);
    x = fmaxf(x, -88.3762626647949f);
    float m = floorf(__builtin_fmaf(x, 1.44269504088896341f, 0.5f));
    float r = __builtin_fmaf(m, -0.693359375f, x);
    r = __builtin_fmaf(m, 2.12194440e-4f, r);
    float z = r * r;
    float y = 1.9875691500E-4f;
    y = __builtin_fmaf(y, r, 1.3981999507E-3f);
    y = __builtin_fmaf(y, r, 8.3334519073E-3f);
    y = __builtin_fmaf(y, r, 4.1665795894E-2f);
    y = __builtin_fmaf(y, r, 1.6666665459E-1f);
    y = __builtin_fmaf(y, r, 5.0000001201E-1f);
    y = __builtin_fmaf(y, z, r);
    y = y + 1.0f;
    return ldexpf(y, (int)m);
}

// verified decode chain (r6) — no fma, op order preserved
__device__ inline float4 decode_box(const float* __restrict__ reg,
                                    const float* __restrict__ anc,
                                    u32 i, bool* valid) {
#pragma clang fp contract(off)
    float x1 = anc[4 * i], y1 = anc[4 * i + 1], x2 = anc[4 * i + 2], y2 = anc[4 * i + 3];
    float acx = (x2 + x1) / 2.0f, acy = (y2 + y1) / 2.0f;
    float aw = x2 - x1, ah = y2 - y1;
    float t0 = reg[4 * i], t1 = reg[4 * i + 1], t2 = reg[4 * i + 2], t3 = reg[4 * i + 3];
    float cx = (t0 * aw) + acx;
    float cy = (t1 * ah) + acy;
    float w  = pexp_f(t2) * aw;
    float hh = pexp_f(t3) * ah;
    float bx1 = fminf(fmaxf(cx - w / 2.0f, 0.f), 1.f);
    float by1 = fminf(fmaxf(cy - hh / 2.0f, 0.f), 1.f);
    float bx2 = fminf(fmaxf(cx + w / 2.0f, 0.f), 1.f);
    float by2 = fminf(fmaxf(cy + hh / 2.0f, 0.f), 1.f);
    float wsz = bx2 - bx1, hsz = by2 - by1;
    *valid = (hsz >= 0.01f) && (wsz >= 0.01f);
    return make_float4(bx1, by1, bx2, by2);
}

// ---------------------------------------------------------------- packed-f32 helpers
// Single-instruction asm: per-lane IEEE f32 mul/add, identical rounding to the
// scalar chain (NO fma). op_sel broadcasts the selected word of src1.
__device__ inline v2f pk_mul_blo(v2f a, v2f b) {
    v2f d;
    asm("v_pk_mul_f32 %0, %1, %2 op_sel:[0,0] op_sel_hi:[1,0]"
        : "=v"(d) : "v"(a), "v"(b));
    return d;
}
__device__ inline v2f pk_mul_bhi(v2f a, v2f b) {
    v2f d;
    asm("v_pk_mul_f32 %0, %1, %2 op_sel:[0,1] op_sel_hi:[1,1]"
        : "=v"(d) : "v"(a), "v"(b));
    return d;
}
__device__ inline v2f pk_add(v2f a, v2f b) {
    v2f d;
    asm("v_pk_add_f32 %0, %1, %2" : "=v"(d) : "v"(a), "v"(b));
    return d;
}

// async global->LDS, 16B per lane; dest = wave-uniform base + lane*16
__device__ inline void gload16(const float* g, void* lds) {
    __builtin_amdgcn_global_load_lds(
        (const __attribute__((address_space(1))) void*)g,
        (__attribute__((address_space(3))) void*)lds,
        16, 0, 0);
}

// ---------------------------------------------------------------- W transpose + zero histograms (replaces 3 memsets)
__global__ __launch_bounds__(256) void wt_k(const float* __restrict__ w,
                                            float* __restrict__ Wt,
                                            u32* __restrict__ hist,
                                            u32* __restrict__ hist2,
                                            u32* __restrict__ counters) {
    int i = blockIdx.x * 256 + threadIdx.x;
    if (i < HIST_BINS) hist[i] = 0;
    if (i < HIST2_BINS) hist2[i] = 0;
    if (i < 64) counters[i] = 0;
    if (i >= 2304 * 256) return;
    int co = i & 255, knew = i >> 8;
    int g = knew >> 8;          // ky*3+kx
    int c = knew & 255;
    Wt[knew * 256 + co] = w[co * 2304 + c * 9 + g];
}

// ---------------------------------------------------------------- fused conv3x3 (all 5 levels, cout-split CS=2)
// Bit-exact Eigen chain: per element, k=(ky,kx,c) ascending, mul/add separate,
// kc=288 panel partials combined left-assoc. r11: 512-thread blocks covering
// 64 consecutive flattened positions — per-thread inner loop identical to r9,
// but W staging per output halves, blocks halve, and LDS 48KB -> 3 blocks x
// 8 waves = 24 waves/CU (75% occupancy vs 43%). Per-lane (yq,xq) via exact
// magic division (sq < 2^17). DOUBLE-BUFFERED LDS (W 2x16KB via
// global_load_lds, X 2x8KB via reg prefetch), one barrier per step.
struct ConvMap {
    const float* feat[5];
    float* part[5];
    const float* Wt;
    const float* bias;
    u64 M[5];                 // magic: floor(x/gw) = (x*M)>>48 for x<2^17
    int bstart[6];
    int st[5], gh[5], gw[5], S[5], npan[5], fuse[5];
};

__global__ __launch_bounds__(512, 4) void conv_all(ConvMap cm)
{
#pragma clang fp contract(off)
    __shared__ float Ws[2][32][128];   // 32 KB
    __shared__ float Xs[2][32][64];    // 16 KB
    const int t  = threadIdx.x;
    const int cg = t & 31, xg = t >> 5;      // xg in 0..15
    const int bid = blockIdx.x;
    const int l = (bid >= cm.bstart[1]) + (bid >= cm.bstart[2]) +
                  (bid >= cm.bstart[3]) + (bid >= cm.bstart[4]);
    const int local = bid - cm.bstart[l];
    const int st = cm.st[l], gh = cm.gh[l], gw = cm.gw[l];
    const int S = cm.S[l], npan = cm.npan[l];
    const float* __restrict__ feat = cm.feat[l];
    const float* __restrict__ Wt   = cm.Wt;
    float* __restrict__ part = cm.part[l];
    const int tile = local % st;
    const int zc   = local / st;
    const int s0   = tile * 64;
    const int z2 = zc & 1, pslot = zc >> 1;
    const int pb   = pslot * npan;
    const int send = (pb + npan) * 9;

    // per-lane (yq, xq) for staged column xcol  (exact magic floor-div)
    const int xcol = t & 63;                 // X staging column 0..63
    const int xrow0 = t >> 6;                // 0..7; X rows xrow0 + 8i
    {
    }
    const int sq = s0 + xcol;
    const int yq = (int)(u32)(((u64)(u32)sq * cm.M[l]) >> 48);
    const int xq = sq - yq * gw;

    const int srow0 = t >> 5;            // 0..15; W rows srow0, srow0+16
    const int wcol  = (t & 31) << 2;     // float col within 128-wide cout half
    const int wvoff = (t >> 6) * 1024;   // wave's byte chunk in a W buffer

    float px0, px1, px2, px3;            // prefetched X (named, never spilled)

#define ISSUE_X(s_) do {                                                       \
        int g_  = (s_) >> 3, cb_ = ((s_) & 7) << 5;                            \
        int ky_ = g_ / 3, kx_ = g_ - ky_ * 3;                                  \
        int yy_ = yq + ky_ - 1;                                                \
        int xx_ = xq + kx_ - 1;                                                \
        bool ok_ = (yy_ >= 0) && (yy_ < gh) && (xx_ >= 0) && (xx_ < gw);       \
        int yyc_ = ok_ ? yy_ : 0;                                              \
        int xcc_ = ok_ ? xx_ : 0;                                              \
        const float* xsrc_ = feat + ((size_t)(cb_ + xrow0) * gh + yyc_) * gw   \
                                  + xcc_;                                      \
        size_t xstr_ = (size_t)(8 * gh) * gw;                                  \
        float xa_ = xsrc_[0];                                                  \
        float xb_ = xsrc_[xstr_];                                              \
        float xc2_ = xsrc_[2 * xstr_];                                         \
        float xd_ = xsrc_[3 * xstr_];                                          \
        px0 = ok_ ? xa_ : 0.f;                                                 \
        px1 = ok_ ? xb_ : 0.f;                                                 \
        px2 = ok_ ? xc2_ : 0.f;                                                \
        px3 = ok_ ? xd_ : 0.f;                                                 \
    } while (0)

#define COMMIT_X(b_) do {                                                      \
        Xs[b_][xrow0][xcol]      = px0;                                        \
        Xs[b_][xrow0 + 8][xcol]  = px1;                                        \
        Xs[b_][xrow0 + 16][xcol] = px2;                                        \
        Xs[b_][xrow0 + 24][xcol] = px3;                                        \
    } while (0)

#define ISSUE_W(s_, b_) do {                                                   \
        int g_  = (s_) >> 3, cb_ = ((s_) & 7) << 5;                            \
        const float* wsrc_ = Wt + ((size_t)(g_ * 256 + cb_ + srow0) * 256)     \
                               + z2 * 128 + wcol;                              \
        char* ldsW_ = (char*)(&Ws[b_][0][0]) + wvoff;                          \
        gload16(wsrc_,        ldsW_);                                          \
        gload16(wsrc_ + 4096, ldsW_ + 8192);                                   \
    } while (0)

    v2f tA0=(v2f)0.f, tA1=(v2f)0.f, tA2=(v2f)0.f, tA3=(v2f)0.f;
    v2f tB0=(v2f)0.f, tB1=(v2f)0.f, tB2=(v2f)0.f, tB3=(v2f)0.f;

    // prologue: stage first step into buf0, prefetch X(next)
    const int sfirst = pb * 9;            // send - sfirst = npan*9 >= 9
    ISSUE_X(sfirst);
    COMMIT_X(0);
    ISSUE_W(sfirst, 0);
    ISSUE_X(sfirst + 1);
    __syncthreads();                      // implied vmcnt/lgkm drain: buf0 ready
    int cur = 0;

    for (int pi = pb; pi < pb + npan; ++pi) {
        v2f pA0=(v2f)0.f, pA1=(v2f)0.f, pA2=(v2f)0.f, pA3=(v2f)0.f;
        v2f pB0=(v2f)0.f, pB1=(v2f)0.f, pB2=(v2f)0.f, pB3=(v2f)0.f;
        for (int j = 0; j < 9; ++j) {
            int s = pi * 9 + j;
            int nxt = cur ^ 1;
            bool more = (s + 1 < send);   // wave-uniform
            if (more) {
                COMMIT_X(nxt);            // px(s+1) -> Xs[nxt]
                ISSUE_W(s + 1, nxt);      // async, lands under kk loop
                if (s + 2 < send) ISSUE_X(s + 2);   // flies under kk loop
            }
            const float* Wb = &Ws[cur][0][0];
            const float* Xb = &Xs[cur][0][0];
#pragma unroll 4
            for (int kk = 0; kk < 32; ++kk) {
                float4 xv = *(const float4*)(Xb + kk * 64 + xg * 4);
                v2f xlo; xlo[0] = xv.x; xlo[1] = xv.y;
                v2f xhi; xhi[0] = xv.z; xhi[1] = xv.w;
                v2f wA = *(const v2f*)(Wb + kk * 128 + cg * 2);
                pA0 = pk_add(pA0, pk_mul_blo(wA, xlo));
                pA1 = pk_add(pA1, pk_mul_bhi(wA, xlo));
                pA2 = pk_add(pA2, pk_mul_blo(wA, xhi));
                pA3 = pk_add(pA3, pk_mul_bhi(wA, xhi));
                v2f wB = *(const v2f*)(Wb + kk * 128 + 64 + cg * 2);
                pB0 = pk_add(pB0, pk_mul_blo(wB, xlo));
                pB1 = pk_add(pB1, pk_mul_bhi(wB, xlo));
                pB2 = pk_add(pB2, pk_mul_blo(wB, xhi));
                pB3 = pk_add(pB3, pk_mul_bhi(wB, xhi));
            }
            if (more) {                   // end-of-step: all reads of cur done,
                __syncthreads();          // staged nxt (W via vmcnt, X via lgkm) visible
                cur = nxt;
            }
        }
        tA0 = pk_add(tA0, pA0); tA1 = pk_add(tA1, pA1);   // left-assoc panel combine
        tA2 = pk_add(tA2, pA2); tA3 = pk_add(tA3, pA3);
        tB0 = pk_add(tB0, pB0); tB1 = pk_add(tB1, pB1);
        tB2 = pk_add(tB2, pB2); tB3 = pk_add(tB3, pB3);
    }
#undef ISSUE_X
#undef COMMIT_X
#undef ISSUE_W
    const int c0 = z2 * 128 + cg * 2;
    if (cm.fuse[l]) {                      // bias+relu, finalize's exact op order
        const float* bias = cm.bias;
        float bA0 = bias[c0], bA1 = bias[c0 + 1];
        float bB0 = bias[c0 + 64], bB1 = bias[c0 + 65];
        tA0[0] = fmaxf(tA0[0] + bA0, 0.f); tA0[1] = fmaxf(tA0[1] + bA1, 0.f);
        tA1[0] = fmaxf(tA1[0] + bA0, 0.f); tA1[1] = fmaxf(tA1[1] + bA1, 0.f);
        tA2[0] = fmaxf(tA2[0] + bA0, 0.f); tA2[1] = fmaxf(tA2[1] + bA1, 0.f);
        tA3[0] = fmaxf(tA3[0] + bA0, 0.f); tA3[1] = fmaxf(tA3[1] + bA1, 0.f);
        tB0[0] = fmaxf(tB0[0] + bB0, 0.f); tB0[1] = fmaxf(tB0[1] + bB1, 0.f);
        tB1[0] = fmaxf(tB1[0] + bB0, 0.f); tB1[1] = fmaxf(tB1[1] + bB1, 0.f);
        tB2[0] = fmaxf(tB2[0] + bB0, 0.f); tB2[1] = fmaxf(tB2[1] + bB1, 0.f);
        tB3[0] = fmaxf(tB3[0] + bB0, 0.f); tB3[1] = fmaxf(tB3[1] + bB1, 0.f);
    }
    float* op = part + (size_t)pslot * 256 * S;
    {
        int sp = s0 + xg * 4;
        size_t rA0 = (size_t)c0 * S + sp;
        size_t rA1 = rA0 + S;
        if (sp + 0 < S) { op[rA0 + 0] = tA0[0]; op[rA1 + 0] = tA0[1]; }
        if (sp + 1 < S) { op[rA0 + 1] = tA1[0]; op[rA1 + 1] = tA1[1]; }
        if (sp + 2 < S) { op[rA0 + 2] = tA2[0]; op[rA1 + 2] = tA2[1]; }
        if (sp + 3 < S) { op[rA0 + 3] = tA3[0]; op[rA1 + 3] = tA3[1]; }
        size_t rB0 = rA0 + (size_t)64 * S;
        size_t rB1 = rB0 + S;
        if (sp + 0 < S) { op[rB0 + 0] = tB0[0]; op[rB1 + 0] = tB0[1]; }
        if (sp + 1 < S) { op[rB0 + 1] = tB1[0]; op[rB1 + 1] = tB1[1]; }
        if (sp + 2 < S) { op[rB0 + 2] = tB2[0]; op[rB1 + 2] = tB2[1]; }
        if (sp + 3 < S) { op[rB0 + 3] = tB3[0]; op[rB1 + 3] = tB3[1]; }
    }
}

// ---------------------------------------------------------------- fused 1x1 heads (+ inline finalize for npan=8 levels)
// For levels 2-4, v is recomputed with finalize's exact op order:
// ((p0+p1+...+p7) + bias, fmax 0) — identical bits.
struct HeadMap {
    const float* h[5];
    int S[5], abase[5], npan[5], bstart[6];
};

__global__ __launch_bounds__(256) void head_all(
    HeadMap hm, const float* __restrict__ wc,
    const float* __restrict__ bc, const float* __restrict__ wr,
    const float* __restrict__ br, const float* __restrict__ bias,
    float* __restrict__ cls_out, float* __restrict__ reg_out)
{
#pragma clang fp contract(off)
    int bid = blockIdx.x;
    int l = (bid >= hm.bstart[1]) + (bid >= hm.bstart[2]) +
            (bid >= hm.bstart[3]) + (bid >= hm.bstart[4]);
    int local = bid - hm.bstart[l];
    const float* __restrict__ h = hm.h[l];
    const int S = hm.S[l];
    const int abase = hm.abase[l];
    const int npan = hm.npan[l];
    int s = local * 256 + threadIdx.x;
    if (s >= S) return;
    float ac[6]  = {0.f};
    float ar[12] = {0.f};
    for (int c = 0; c < 256; ++c) {
        size_t i = (size_t)c * S + s;
        float v;
        if (npan == 1) {
            v = h[i];
        } else {
            float vv = h[i];
            for (int p = 1; p < 8; ++p)
                vv = vv + h[(size_t)p * 256 * S + i];   // strict panel order
            v = fmaxf(vv + bias[c], 0.f);
        }
#pragma unroll
        for (int ch = 0; ch < 6; ++ch) {
            float prod = wc[ch * 256 + c] * v;
            ac[ch] = ac[ch] + prod;
        }
#pragma unroll
        for (int ch = 0; ch < 12; ++ch) {
            float prod = wr[ch * 256 + c] * v;
            ar[ch] = ar[ch] + prod;
        }
    }
    long b2 = (long)abase + (long)s * 3;
#pragma unroll
    for (int a = 0; a < 3; ++a) {
#pragma unroll
        for (int c2 = 0; c2 < 2; ++c2)
            cls_out[(b2 + a) * 2 + c2] = ac[a * 2 + c2] + bc[a * 2 + c2];
#pragma unroll
        for (int d = 0; d < 4; ++d)
            reg_out[(b2 + a) * 4 + d] = ar[a * 4 + d] + br[a * 4 + d];
    }
}

// ---------------------------------------------------------------- f32 score + key + hist (+ anchors inline, bit-identical)
__global__ __launch_bounds__(256) void score_k(
    const float* __restrict__ cls, const float* __restrict__ reg,
    BaseTab bt, u64* __restrict__ keys, u32* __restrict__ hist,
    float* __restrict__ anc_out)
{
#pragma clang fp contract(off)
    int i = blockIdx.x * 256 + threadIdx.x;
    if (i >= A_TOT) return;
    // ---- anchor (same expressions as the old anchors_k)
    int l, base, gw, str;
    if (i < 120000)      { l = 0; base = 0;      gw = 200; str = 4;  }
    else if (i < 150000) { l = 1; base = 120000; gw = 100; str = 8;  }
    else if (i < 157500) { l = 2; base = 150000; gw = 50;  str = 16; }
    else if (i < 159375) { l = 3; base = 157500; gw = 25;  str = 32; }
    else                 { l = 4; base = 159375; gw = 13;  str = 61; }
    int j = i - base;
    int sj = j / 3;
    int a = j - sj * 3;
    int yy = sj / gw;
    int xx = sj - yy * gw;
    float sx = (float)(xx * str), sy = (float)(yy * str);
    const float* bb = &bt.v[(l * 3 + a) * 4];
    float a0 = (sx + bb[0]) / 800.0f;
    float a1 = (sy + bb[1]) / 800.0f;
    float a2 = (sx + bb[2]) / 800.0f;
    float a3 = (sy + bb[3]) / 800.0f;
    anc_out[4 * i + 0] = a0;
    anc_out[4 * i + 1] = a1;
    anc_out[4 * i + 2] = a2;
    anc_out[4 * i + 3] = a3;
    // ---- softmax score
    float l0 = cls[2 * i], l1 = cls[2 * i + 1];
    float m  = fmaxf(l0, l1);
    float e0 = pexp_f(l0 - m);
    float e1 = pexp_f(l1 - m);
    float sum = e0 + e1;
    float sc  = e1 / sum;
    // ---- validity (decode chain, same op order; only valid used)
    float acx = (a2 + a0) / 2.0f, acy = (a3 + a1) / 2.0f;
    float aw = a2 - a0, ah = a3 - a1;
    float t0 = reg[4 * i], t1 = reg[4 * i + 1], t2 = reg[4 * i + 2], t3 = reg[4 * i + 3];
    float cx = (t0 * aw) + acx;
    float cy = (t1 * ah) + acy;
    float w  = pexp_f(t2) * aw;
    float hh = pexp_f(t3) * ah;
    float bx1 = fminf(fmaxf(cx - w / 2.0f, 0.f), 1.f);
    float by1 = fminf(fmaxf(cy - hh / 2.0f, 0.f), 1.f);
    float bx2 = fminf(fmaxf(cx + w / 2.0f, 0.f), 1.f);
    float by2 = fminf(fmaxf(cy + hh / 2.0f, 0.f), 1.f);
    float wsz = bx2 - bx1, hsz = by2 - by1;
    bool valid = (hsz >= 0.01f) && (wsz >= 0.01f);

    float score = valid ? sc : -INFINITY;
    u32 u = mono32f(score);
    keys[i] = ((u64)u << 32) | (u32)(~(u32)i);   // desc score, asc index
    atomicAdd(&hist[u >> 15], 1u);
}

// ---------------------------------------------------------------- coarse threshold bin
__global__ __launch_bounds__(1024) void topk_thresh(const u32* __restrict__ hist,
                                                    u32* __restrict__ counters) {
    __shared__ u32 part[1024];
    int t = threadIdx.x;
    u32 s = 0;
    for (int q = 0; q < 128; ++q) s += hist[HIST_BINS - 1 - (t * 128 + q)];
    part[t] = s;
    __syncthreads();
    if (t == 0) {
        u32 cum = 0, cumBefore = 0;
        int tc = 1023;
        for (int c = 0; c < 1024; ++c) {
            if (cum + part[c] >= PRE_NMS) { tc = c; cumBefore = cum; break; }
            cum += part[c];
        }
        u32 cum2 = cumBefore;
        int bstar = 0;
        for (int q = 0; q < 128; ++q) {
            int b = HIST_BINS - 1 - (tc * 128 + q);
            u32 hv = hist[b];
            if (cum2 + hv >= PRE_NMS) { bstar = b; break; }
            cum2 += hv;
        }
        counters[0] = (u32)bstar;
        counters[1] = cum2;
    }
}

// ---------------------------------------------------------------- fine histogram in bstar bin
__global__ __launch_bounds__(256) void hist2_k(const u64* __restrict__ keys,
                                               const u32* __restrict__ counters,
                                               u32* __restrict__ hist2) {
    int i = blockIdx.x * 256 + threadIdx.x;
    if (i >= A_TOT) return;
    u32 u = (u32)(keys[i] >> 32);
    if ((u >> 15) == counters[0]) atomicAdd(&hist2[u & 0x7FFF], 1u);
}

// ---------------------------------------------------------------- exact 32-bit cutoff
__global__ __launch_bounds__(1024) void thresh2_k(const u32* __restrict__ hist2,
                                                  u32* __restrict__ counters) {
    __shared__ u32 part[1024];
    int t = threadIdx.x;
    u32 s = 0;
    for (int q = 0; q < 32; ++q) s += hist2[HIST2_BINS - 1 - (t * 32 + q)];
    part[t] = s;
    __syncthreads();
    if (t == 0) {
        u32 bstar = counters[0];
        u32 cum = counters[1];
        int tc = 1023;
        u32 cumBefore = cum;
        for (int c = 0; c < 1024; ++c) {
            if (cum + part[c] >= PRE_NMS) { tc = c; cumBefore = cum; break; }
            cum += part[c];
        }
        u32 cum2 = cumBefore;
        u32 low = 0;
        for (int q = 0; q < 32; ++q) {
            int b = HIST2_BINS - 1 - (tc * 32 + q);
            u32 hv = hist2[b];
            if (cum2 + hv >= PRE_NMS) { low = (u32)b; break; }
            cum2 += hv;
        }
        counters[3] = (bstar << 15) | low;   // exact monotone-u cutoff
    }
}

// ---------------------------------------------------------------- compact survivors (exact)
__global__ __launch_bounds__(256) void compact_k(const u64* __restrict__ keys,
                                                 u32* __restrict__ counters,
                                                 u64* __restrict__ surv) {
    int i = blockIdx.x * 256 + threadIdx.x;
    if (i >= A_TOT) return;
    u32 cut = counters[3];
    u64 k = keys[i];
    if ((u32)(k >> 32) >= cut) {
        u32 slot = atomicAdd(&counters[2], 1u);
        if (slot < SURV_CAP) surv[slot] = k;
    }
}

// ---------------------------------------------------------------- bitonic sort + gather (recompute decode)
// Adaptive size: if n <= 4096 sort 4096 (78 passes) else 8192 (91). Zeros sort
// to the back either way; first PRE_NMS entries identical -> bit-exact.
__global__ __launch_bounds__(1024) void sort_topk(
    const u64* __restrict__ surv, const u32* __restrict__ counters,
    const float* __restrict__ reg, const float* __restrict__ anc,
    float* __restrict__ boxes4k, u64* __restrict__ finmask)
{
    __shared__ u64 K[SURV_CAP];   // 64 KB
    int t = threadIdx.x;
    u32 n = counters[2];
    if (n > SURV_CAP) n = SURV_CAP;
    const int msize = (n <= 4096) ? 4096 : SURV_CAP;
    for (int p = t; p < msize; p += 1024) K[p] = (p < (int)n) ? surv[p] : 0ull;
    __syncthreads();
    for (int k = 2; k <= msize; k <<= 1) {
        for (int j = k >> 1; j > 0; j >>= 1) {
            for (int p = t; p < msize / 2; p += 1024) {
                int i = 2 * p - (p & (j - 1));
                int pr = i + j;
                bool desc = ((i & k) == 0);
                u64 a = K[i], b = K[pr];
                if (desc ? (a < b) : (a > b)) { K[i] = b; K[pr] = a; }
            }
            __syncthreads();
        }
    }
    for (int jj = t; jj < PRE_NMS; jj += 1024) {
        u64 key = K[jj];
        u32 u = (u32)(key >> 32);
        float b0 = 0.f, b1 = 0.f, b2 = 0.f, b3 = 0.f;
        if (u > MONO_NEG_INF) {
            u32 idx = ~(u32)key;
            bool valid;
            float4 bx = decode_box(reg, anc, idx, &valid);
            b0 = bx.x; b1 = bx.y; b2 = bx.z; b3 = bx.w;
        }
        boxes4k[4 * jj + 0] = b0;
        boxes4k[4 * jj + 1] = b1;
        boxes4k[4 * jj + 2] = b2;
        boxes4k[4 * jj + 3] = b3;
    }
    if (t < NWORDS) {
        u64 wmask = 0;
        for (int b = 0; b < 64; ++b) {
            int jj = t * 64 + b;
            if (jj < PRE_NMS) {
                u32 u = (u32)(K[jj] >> 32);
                if (u > MONO_NEG_INF) wmask |= (1ull << b);
            }
        }
        finmask[t] = wmask;
    }
}

// ---------------------------------------------------------------- suppression matrix (f32, np op order)
__global__ __launch_bounds__(64) void supmat_k(const float* __restrict__ boxes4k,
                                               u64* __restrict__ sup) {
#pragma clang fp contract(off)
    __shared__ float cb[64][4];
    int rb = blockIdx.y, cbk = blockIdx.x;
    int tl = threadIdx.x;
    int j = cbk * 64 + tl;
    if (j < PRE_NMS) {
        cb[tl][0] = boxes4k[4 * j + 0];
        cb[tl][1] = boxes4k[4 * j + 1];
        cb[tl][2] = boxes4k[4 * j + 2];
        cb[tl][3] = boxes4k[4 * j + 3];
    } else {
        cb[tl][0] = cb[tl][1] = cb[tl][2] = cb[tl][3] = 0.f;
    }
    __syncthreads();
    int i = rb * 64 + tl;
    if (i >= PRE_NMS) return;
    float ax1 = boxes4k[4 * i + 0], ay1 = boxes4k[4 * i + 1];
    float ax2 = boxes4k[4 * i + 2], ay2 = boxes4k[4 * i + 3];
    float aarea = fmaxf(ax2 - ax1, 0.f) * fmaxf(ay2 - ay1, 0.f);
    u64 w = 0;
    for (int q = 0; q < 64; ++q) {
        int jg = cbk * 64 + q;
        if (jg >= PRE_NMS || jg <= i) continue;
        float bx1 = cb[q][0], by1 = cb[q][1], bx2 = cb[q][2], by2 = cb[q][3];
        float barea = fmaxf(bx2 - bx1, 0.f) * fmaxf(by2 - by1, 0.f);
        float lx = fmaxf(ax1, bx1), ly = fmaxf(ay1, by1);
        float rx = fminf(ax2, bx2), ry = fminf(ay2, by2);
        float iw = fmaxf(rx - lx, 0.f), ih = fmaxf(ry - ly, 0.f);
        float inter = iw * ih;
        float uni = (aarea + barea) - inter;
        float iou = (uni > 0.f) ? inter / uni : 0.f;
        if (iou > 0.7f) w |= (1ull << q);
    }
    sup[(size_t)i * NWORDS + cbk] = w;
}

// ---------------------------------------------------------------- sequential NMS scan + output (merged, depth-3 prefetch)
__device__ inline u64 shfl_u64(u64 v, int lane) {
    int lo = __shfl((int)(u32)(v & 0xFFFFFFFFull), lane, 64);
    int hi = __shfl((int)(u32)(v >> 32), lane, 64);
    return ((u64)(u32)hi << 32) | (u32)lo;
}

__global__ __launch_bounds__(256) void nms_out_k(const u64* __restrict__ sup,
                                                 const u64* __restrict__ finmask,
                                                 const float* __restrict__ boxes4k,
                                                 float* __restrict__ roi_out) {
    __shared__ u64 keepw_s[NWORDS];
    __shared__ u32 pref[NWORDS + 1];
    int t = threadIdx.x;
    if (t < 64) {
        int lane = t;
        u64 keep = (lane < NWORDS) ? finmask[lane] : 0ull;
        u64 cur[8], n1[8], n2[8], nw[8];
#define LDROW(dst_, i0_)                                                       \
        _Pragma("unroll")                                                      \
        for (int q = 0; q < 8; ++q) {                                          \
            int i_ = (i0_) + q;                                                \
            dst_[q] = (lane < NWORDS && i_ < PRE_NMS)                          \
                      ? sup[(size_t)i_ * NWORDS + lane] : 0ull;                \
        }
        LDROW(cur, 0)
        LDROW(n1, 8)
        LDROW(n2, 16)
        for (int base = 0; base < PRE_NMS; base += 8) {
            LDROW(nw, base + 24)          // 24 rows in flight over this body
#pragma unroll
            for (int q = 0; q < 8; ++q) {
                int i = base + q;
                int wi = i >> 6, bi = i & 63;
                u64 kw = shfl_u64(keep, wi);
                if ((kw >> bi) & 1ull) keep &= ~cur[q];
            }
#pragma unroll
            for (int q = 0; q < 8; ++q) { cur[q] = n1[q]; n1[q] = n2[q]; n2[q] = nw[q]; }
        }
#undef LDROW
        if (lane < NWORDS) keepw_s[lane] = keep;
    }
    __syncthreads();
    if (t == 0) {
        u32 run = 0;
        for (int w = 0; w < NWORDS; ++w) { pref[w] = run; run += (u32)__popcll(keepw_s[w]); }
        pref[NWORDS] = run;
    }
    __syncthreads();
    u32 total = pref[NWORDS];
    u32 nk = total < (u32)POST_NMS ? total : (u32)POST_NMS;
    for (int j = t; j < PRE_NMS; j += 256) {
        int wi = j >> 6, bi = j & 63;
        u64 kw = keepw_s[wi];
        if ((kw >> bi) & 1ull) {
            u32 rank = pref[wi] + (u32)__popcll(kw & ((1ull << bi) - 1ull));
            if (rank < (u32)POST_NMS) {
                roi_out[4 * rank + 0] = boxes4k[4 * j + 0];
                roi_out[4 * rank + 1] = boxes4k[4 * j + 1];
                roi_out[4 * rank + 2] = boxes4k[4 * j + 2];
                roi_out[4 * rank + 3] = boxes4k[4 * j + 3];
            }
        }
    }
    for (int r2 = t; r2 < POST_NMS; r2 += 256) {
        if ((u32)r2 >= nk) {
            roi_out[4 * r2 + 0] = 0.f;
            roi_out[4 * r2 + 1] = 0.f;
            roi_out[4 * r2 + 2] = 0.f;
            roi_out[4 * r2 + 3] = 0.f;
        }
    }
}

// ================================================================ host
extern "C" void kernel_launch(void* const* d_in, const int* in_sizes, int n_in,
                              void* d_out, int out_size, void* d_ws, size_t ws_size,
                              hipStream_t stream) {
    const float* feat[5] = {
        (const float*)d_in[1], (const float*)d_in[2], (const float*)d_in[3],
        (const float*)d_in[4], (const float*)d_in[5]};
    const float* w_inter = (const float*)d_in[6];
    const float* b_inter = (const float*)d_in[7];
    const float* w_cls   = (const float*)d_in[8];
    const float* b_cls   = (const float*)d_in[9];
    const float* w_reg   = (const float*)d_in[10];
    const float* b_reg   = (const float*)d_in[11];

    float* out     = (float*)d_out;
    float* out_cls = out;                       // 159882*2
    float* out_reg = out + 319764;              // 159882*4
    float* out_roi = out + 959292;              // 1000*4
    float* out_anc = out + 963292;              // 159882*4

    static const int GH[5]    = {200, 100, 50, 25, 13};
    static const int GW[5]    = {200, 100, 50, 25, 13};
    static const int SL[5]    = {40000, 10000, 2500, 625, 169};
    static const int ABASE[5] = {0, 120000, 150000, 157500, 159375};
    static const int NPAN_ST[5] = {1, 1, 8, 8, 8};   // panel-partial slots stored

    // ---- workspace carve (~85 MB total)
    char* p = (char*)d_ws;
    size_t off = 0;
    auto alloc = [&](size_t bytes) -> void* {
        void* r = p + off;
        off = (off + bytes + 255) & ~(size_t)255;
        return r;
    };
    float* Wt      = (float*)alloc((size_t)2304 * 256 * 4);
    float* part[5];
    for (int l = 0; l < 5; ++l)
        part[l] = (float*)alloc((size_t)NPAN_ST[l] * 256 * SL[l] * 4);
    u64*   keys    = (u64*)  alloc((size_t)A_TOT * 8);
    u32*   hist    = (u32*)  alloc((size_t)HIST_BINS * 4);
    u32*   hist2   = (u32*)  alloc((size_t)HIST2_BINS * 4);
    u32*   counters= (u32*)  alloc(256);
    u64*   surv    = (u64*)  alloc((size_t)SURV_CAP * 8);
    float* boxes4k = (float*)alloc((size_t)PRE_NMS * 4 * 4);
    u64*   finmask = (u64*)  alloc(64 * 8);
    u64*   supmat  = (u64*)  alloc((size_t)PRE_NMS * NWORDS * 8);
    (void)ws_size;

    // ---- host anchor base table, float32 to match np (round half-even)
    BaseTab bt;
    {
        const float sizes[5] = {32.f, 64.f, 128.f, 256.f, 512.f};
        const float asp[3] = {0.5f, 1.0f, 2.0f};
        for (int l = 0; l < 5; ++l)
            for (int a = 0; a < 3; ++a) {
                float hr = sqrtf(asp[a]);
                float wr = 1.0f / hr;
                float wsf = sizes[l] * wr;
                float hsf = sizes[l] * hr;
                bt.v[(l * 3 + a) * 4 + 0] = rintf(-wsf / 2.0f);
                bt.v[(l * 3 + a) * 4 + 1] = rintf(-hsf / 2.0f);
                bt.v[(l * 3 + a) * 4 + 2] = rintf( wsf / 2.0f);
                bt.v[(l * 3 + a) * 4 + 3] = rintf( hsf / 2.0f);
            }
    }

    wt_k<<<2304, 256, 0, stream>>>(w_inter, Wt, hist, hist2, counters);

    // ---- fused conv (all 5 levels, one launch, 64-position linear tiles)
    ConvMap cm;
    cm.Wt = Wt;
    cm.bias = b_inter;
    int bacc = 0;
    for (int l = 0; l < 5; ++l) {
        cm.feat[l] = feat[l];
        cm.part[l] = part[l];
        int st = (SL[l] + 63) / 64;
        cm.st[l] = st; cm.gh[l] = GH[l]; cm.gw[l] = GW[l]; cm.S[l] = SL[l];
        cm.M[l] = (((u64)1 << 48) + (u64)GW[l] - 1) / (u64)GW[l];
        int zsplit = NPAN_ST[l];
        cm.npan[l] = (zsplit == 1) ? 8 : 1;
        cm.fuse[l] = (zsplit == 1) ? 1 : 0;       // bias+relu fused for levels 0/1
        cm.bstart[l] = bacc;
        bacc += st * (zsplit * 2);
    }
    cm.bstart[5] = bacc;
    conv_all<<<bacc, 512, 0, stream>>>(cm);

    // ---- fused heads (finalize for levels 2-4 done inline)
    HeadMap hm;
    int hacc = 0;
    for (int l = 0; l < 5; ++l) {
        hm.h[l] = part[l];
        hm.S[l] = SL[l];
        hm.abase[l] = ABASE[l];
        hm.npan[l] = NPAN_ST[l];
        hm.bstart[l] = hacc;
        hacc += (SL[l] + 255) / 256;
    }
    hm.bstart[5] = hacc;
    head_all<<<hacc, 256, 0, stream>>>(hm, w_cls, b_cls, w_reg, b_reg,
                                       b_inter, out_cls, out_reg);

    int nbA = (A_TOT + 255) / 256;
    score_k<<<nbA, 256, 0, stream>>>(out_cls, out_reg, bt, keys, hist, out_anc);
    topk_thresh<<<1, 1024, 0, stream>>>(hist, counters);
    hist2_k<<<nbA, 256, 0, stream>>>(keys, counters, hist2);
    thresh2_k<<<1, 1024, 0, stream>>>(hist2, counters);
    compact_k<<<nbA, 256, 0, stream>>>(keys, counters, surv);
    sort_topk<<<1, 1024, 0, stream>>>(surv, counters, out_reg, out_anc, boxes4k, finmask);
    supmat_k<<<dim3(NWORDS, NWORDS), 64, 0, stream>>>(boxes4k, supmat);
    nms_out_k<<<1, 256, 0, stream>>>(supmat, finmask, boxes4k, out_roi);
}

// Round 12
// 2351.233 us; speedup vs baseline: 1.0773x; 1.0628x over previous
//
#include <hip/hip_runtime.h>
#include <cmath>
#include <cstdint>

typedef unsigned int u32;
typedef unsigned long long u64;
typedef float v2f __attribute__((ext_vector_type(2)));

#define A_TOT   159882
#define PRE_NMS 4000
#define POST_NMS 1000
#define NWORDS  63            // ceil(4000/64)
#define HIST_BINS 131072
#define HIST2_BINS 32768
#define SURV_CAP 8192
#define MONO_NEG_INF 0x007FFFFFu

struct BaseTab { float v[60]; };   // [level][aspect][4]

__device__ inline u32 mono32f(float s) {
    u32 u = __float_as_uint(s);
    return (u & 0x80000000u) ? ~u : (u | 0x80000000u);
}

// XLA:CPU / cephes vectorized expf (verified passing in r6 — DO NOT TOUCH)
__device__ inline float pexp_f(float x0) {
    float x = fminf(x0, 88.3762626647950f);
    x = fmaxf(x, -88.3762626647949f);
    float m = floorf(__builtin_fmaf(x, 1.44269504088896341f, 0.5f));
    float r = __builtin_fmaf(m, -0.693359375f, x);
    r = __builtin_fmaf(m, 2.12194440e-4f, r);
    float z = r * r;
    float y = 1.9875691500E-4f;
    y = __builtin_fmaf(y, r, 1.3981999507E-3f);
    y = __builtin_fmaf(y, r, 8.3334519073E-3f);
    y = __builtin_fmaf(y, r, 4.1665795894E-2f);
    y = __builtin_fmaf(y, r, 1.6666665459E-1f);
    y = __builtin_fmaf(y, r, 5.0000001201E-1f);
    y = __builtin_fmaf(y, z, r);
    y = y + 1.0f;
    return ldexpf(y, (int)m);
}

// verified decode chain (r6) — no fma, op order preserved
__device__ inline float4 decode_box(const float* __restrict__ reg,
                                    const float* __restrict__ anc,
                                    u32 i, bool* valid) {
#pragma clang fp contract(off)
    float x1 = anc[4 * i], y1 = anc[4 * i + 1], x2 = anc[4 * i + 2], y2 = anc[4 * i + 3];
    float acx = (x2 + x1) / 2.0f, acy = (y2 + y1) / 2.0f;
    float aw = x2 - x1, ah = y2 - y1;
    float t0 = reg[4 * i], t1 = reg[4 * i + 1], t2 = reg[4 * i + 2], t3 = reg[4 * i + 3];
    float cx = (t0 * aw) + acx;
    float cy = (t1 * ah) + acy;
    float w  = pexp_f(t2) * aw;
    float hh = pexp_f(t3) * ah;
    float bx1 = fminf(fmaxf(cx - w / 2.0f, 0.f), 1.f);
    float by1 = fminf(fmaxf(cy - hh / 2.0f, 0.f), 1.f);
    float bx2 = fminf(fmaxf(cx + w / 2.0f, 0.f), 1.f);
    float by2 = fminf(fmaxf(cy + hh / 2.0f, 0.f), 1.f);
    float wsz = bx2 - bx1, hsz = by2 - by1;
    *valid = (hsz >= 0.01f) && (wsz >= 0.01f);
    return make_float4(bx1, by1, bx2, by2);
}

// ---------------------------------------------------------------- packed-f32 helpers
// Single-instruction asm: per-lane IEEE f32 mul/add, identical rounding to the
// scalar chain (NO fma). op_sel broadcasts the selected word of src1.
__device__ inline v2f pk_mul_blo(v2f a, v2f b) {
    v2f d;
    asm("v_pk_mul_f32 %0, %1, %2 op_sel:[0,0] op_sel_hi:[1,0]"
        : "=v"(d) : "v"(a), "v"(b));
    return d;
}
__device__ inline v2f pk_mul_bhi(v2f a, v2f b) {
    v2f d;
    asm("v_pk_mul_f32 %0, %1, %2 op_sel:[0,1] op_sel_hi:[1,1]"
        : "=v"(d) : "v"(a), "v"(b));
    return d;
}
__device__ inline v2f pk_add(v2f a, v2f b) {
    v2f d;
    asm("v_pk_add_f32 %0, %1, %2" : "=v"(d) : "v"(a), "v"(b));
    return d;
}

// async global->LDS, 16B per lane; dest = wave-uniform base + lane*16
__device__ inline void gload16(const float* g, void* lds) {
    __builtin_amdgcn_global_load_lds(
        (const __attribute__((address_space(1))) void*)g,
        (__attribute__((address_space(3))) void*)lds,
        16, 0, 0);
}

// ---------------------------------------------------------------- W transpose + zero histograms (replaces 3 memsets)
__global__ __launch_bounds__(256) void wt_k(const float* __restrict__ w,
                                            float* __restrict__ Wt,
                                            u32* __restrict__ hist,
                                            u32* __restrict__ hist2,
                                            u32* __restrict__ counters) {
    int i = blockIdx.x * 256 + threadIdx.x;
    if (i < HIST_BINS) hist[i] = 0;
    if (i < HIST2_BINS) hist2[i] = 0;
    if (i < 64) counters[i] = 0;
    if (i >= 2304 * 256) return;
    int co = i & 255, knew = i >> 8;
    int g = knew >> 8;          // ky*3+kx
    int c = knew & 255;
    Wt[knew * 256 + co] = w[co * 2304 + c * 9 + g];
}

// ---------------------------------------------------------------- fused conv3x3 (all 5 levels, cout-split CS=2)
// Bit-exact Eigen chain: per element, k=(ky,kx,c) ascending, mul/add separate,
// kc=288 panel partials combined left-assoc. LINEAR-POSITION tiling: each block
// covers 32 consecutive flattened positions (zero x-padding). DOUBLE-BUFFERED
// LDS (W 2x16KB via global_load_lds, X 2x4KB via reg prefetch), one barrier
// per step. Best-known config (r9): 256thr / 32-pos / b128 x-read / unroll 4.
// r10 (2xb64) and r11 (512thr/64-pos) both regressed — this is a local optimum.
struct ConvMap {
    const float* feat[5];
    float* part[5];
    const float* Wt;
    const float* bias;
    u64 M[5];                 // magic: floor(x/gw) = (x*M)>>48 for x<2^17
    int bstart[6];
    int st[5], gh[5], gw[5], S[5], npan[5], fuse[5];
};

__global__ __launch_bounds__(256, 4) void conv_all(ConvMap cm)
{
#pragma clang fp contract(off)
    __shared__ float Ws[2][32][128];   // 32 KB
    __shared__ float Xs[2][32][32];    // 8 KB
    const int t  = threadIdx.x;
    const int cg = t & 31, xg = t >> 5;
    const int bid = blockIdx.x;
    const int l = (bid >= cm.bstart[1]) + (bid >= cm.bstart[2]) +
                  (bid >= cm.bstart[3]) + (bid >= cm.bstart[4]);
    const int local = bid - cm.bstart[l];
    const int st = cm.st[l], gh = cm.gh[l], gw = cm.gw[l];
    const int S = cm.S[l], npan = cm.npan[l];
    const float* __restrict__ feat = cm.feat[l];
    const float* __restrict__ Wt   = cm.Wt;
    float* __restrict__ part = cm.part[l];
    const int tile = local % st;
    const int zc   = local / st;
    const int s0   = tile * 32;
    const int z2 = zc & 1, pslot = zc >> 1;
    const int pb   = pslot * npan;
    const int send = (pb + npan) * 9;

    // per-lane (yq, xq) for staged column cg  (bit-identical padding decode)
    const u32 y00 = (u32)(((u64)(u32)s0 * cm.M[l]) >> 48);
    const int x00 = s0 - (int)y00 * gw;
    int xq = x00 + cg;
    int yq = (int)y00;
#pragma unroll
    for (int r = 0; r < 3; ++r) { if (xq >= gw) { xq -= gw; ++yq; } }

    const int srow0 = t >> 5;            // 0..7; rows srow0 + 8i
    const int wcol  = (t & 31) << 2;     // float col within 128-wide cout half
    const int wvoff = (t >> 6) * 1024;   // wave's byte chunk in a W buffer

    float px0, px1, px2, px3;            // prefetched X (named, never spilled)

#define ISSUE_X(s_) do {                                                       \
        int g_  = (s_) >> 3, cb_ = ((s_) & 7) << 5;                            \
        int ky_ = g_ / 3, kx_ = g_ - ky_ * 3;                                  \
        int yy_ = yq + ky_ - 1;                                                \
        int xx_ = xq + kx_ - 1;                                                \
        bool ok_ = (yy_ >= 0) && (yy_ < gh) && (xx_ >= 0) && (xx_ < gw);       \
        int yyc_ = ok_ ? yy_ : 0;                                              \
        int xcc_ = ok_ ? xx_ : 0;                                              \
        const float* xsrc_ = feat + ((size_t)(cb_ + srow0) * gh + yyc_) * gw   \
                                  + xcc_;                                      \
        size_t xstr_ = (size_t)(8 * gh) * gw;                                  \
        float xa_ = xsrc_[0];                                                  \
        float xb_ = xsrc_[xstr_];                                              \
        float xc2_ = xsrc_[2 * xstr_];                                         \
        float xd_ = xsrc_[3 * xstr_];                                          \
        px0 = ok_ ? xa_ : 0.f;                                                 \
        px1 = ok_ ? xb_ : 0.f;                                                 \
        px2 = ok_ ? xc2_ : 0.f;                                                \
        px3 = ok_ ? xd_ : 0.f;                                                 \
    } while (0)

#define COMMIT_X(b_) do {                                                      \
        Xs[b_][srow0][cg]      = px0;                                          \
        Xs[b_][srow0 + 8][cg]  = px1;                                          \
        Xs[b_][srow0 + 16][cg] = px2;                                          \
        Xs[b_][srow0 + 24][cg] = px3;                                          \
    } while (0)

#define ISSUE_W(s_, b_) do {                                                   \
        int g_  = (s_) >> 3, cb_ = ((s_) & 7) << 5;                            \
        const float* wsrc_ = Wt + ((size_t)(g_ * 256 + cb_ + srow0) * 256)     \
                               + z2 * 128 + wcol;                              \
        char* ldsW_ = (char*)(&Ws[b_][0][0]) + wvoff;                          \
        gload16(wsrc_,        ldsW_);                                          \
        gload16(wsrc_ + 2048, ldsW_ + 4096);                                   \
        gload16(wsrc_ + 4096, ldsW_ + 8192);                                   \
        gload16(wsrc_ + 6144, ldsW_ + 12288);                                  \
    } while (0)

    v2f tA0=(v2f)0.f, tA1=(v2f)0.f, tA2=(v2f)0.f, tA3=(v2f)0.f;
    v2f tB0=(v2f)0.f, tB1=(v2f)0.f, tB2=(v2f)0.f, tB3=(v2f)0.f;

    // prologue: stage first step into buf0, prefetch X(next)
    const int sfirst = pb * 9;            // send - sfirst = npan*9 >= 9
    ISSUE_X(sfirst);
    COMMIT_X(0);
    ISSUE_W(sfirst, 0);
    ISSUE_X(sfirst + 1);
    __syncthreads();                      // implied vmcnt/lgkm drain: buf0 ready
    int cur = 0;

    for (int pi = pb; pi < pb + npan; ++pi) {
        v2f pA0=(v2f)0.f, pA1=(v2f)0.f, pA2=(v2f)0.f, pA3=(v2f)0.f;
        v2f pB0=(v2f)0.f, pB1=(v2f)0.f, pB2=(v2f)0.f, pB3=(v2f)0.f;
        for (int j = 0; j < 9; ++j) {
            int s = pi * 9 + j;
            int nxt = cur ^ 1;
            bool more = (s + 1 < send);   // wave-uniform
            if (more) {
                COMMIT_X(nxt);            // px(s+1) -> Xs[nxt]
                ISSUE_W(s + 1, nxt);      // async, lands under kk loop
                if (s + 2 < send) ISSUE_X(s + 2);   // flies under kk loop
            }
            const float* Wb = &Ws[cur][0][0];
            const float* Xb = &Xs[cur][0][0];
#pragma unroll 4
            for (int kk = 0; kk < 32; ++kk) {
                float4 xv = *(const float4*)(Xb + kk * 32 + xg * 4);
                v2f xlo; xlo[0] = xv.x; xlo[1] = xv.y;
                v2f xhi; xhi[0] = xv.z; xhi[1] = xv.w;
                v2f wA = *(const v2f*)(Wb + kk * 128 + cg * 2);
                pA0 = pk_add(pA0, pk_mul_blo(wA, xlo));
                pA1 = pk_add(pA1, pk_mul_bhi(wA, xlo));
                pA2 = pk_add(pA2, pk_mul_blo(wA, xhi));
                pA3 = pk_add(pA3, pk_mul_bhi(wA, xhi));
                v2f wB = *(const v2f*)(Wb + kk * 128 + 64 + cg * 2);
                pB0 = pk_add(pB0, pk_mul_blo(wB, xlo));
                pB1 = pk_add(pB1, pk_mul_bhi(wB, xlo));
                pB2 = pk_add(pB2, pk_mul_blo(wB, xhi));
                pB3 = pk_add(pB3, pk_mul_bhi(wB, xhi));
            }
            if (more) {                   // end-of-step: all reads of cur done,
                __syncthreads();          // staged nxt (W via vmcnt, X via lgkm) visible
                cur = nxt;
            }
        }
        tA0 = pk_add(tA0, pA0); tA1 = pk_add(tA1, pA1);   // left-assoc panel combine
        tA2 = pk_add(tA2, pA2); tA3 = pk_add(tA3, pA3);
        tB0 = pk_add(tB0, pB0); tB1 = pk_add(tB1, pB1);
        tB2 = pk_add(tB2, pB2); tB3 = pk_add(tB3, pB3);
    }
#undef ISSUE_X
#undef COMMIT_X
#undef ISSUE_W
    const int c0 = z2 * 128 + cg * 2;
    if (cm.fuse[l]) {                      // bias+relu, finalize's exact op order
        const float* bias = cm.bias;
        float bA0 = bias[c0], bA1 = bias[c0 + 1];
        float bB0 = bias[c0 + 64], bB1 = bias[c0 + 65];
        tA0[0] = fmaxf(tA0[0] + bA0, 0.f); tA0[1] = fmaxf(tA0[1] + bA1, 0.f);
        tA1[0] = fmaxf(tA1[0] + bA0, 0.f); tA1[1] = fmaxf(tA1[1] + bA1, 0.f);
        tA2[0] = fmaxf(tA2[0] + bA0, 0.f); tA2[1] = fmaxf(tA2[1] + bA1, 0.f);
        tA3[0] = fmaxf(tA3[0] + bA0, 0.f); tA3[1] = fmaxf(tA3[1] + bA1, 0.f);
        tB0[0] = fmaxf(tB0[0] + bB0, 0.f); tB0[1] = fmaxf(tB0[1] + bB1, 0.f);
        tB1[0] = fmaxf(tB1[0] + bB0, 0.f); tB1[1] = fmaxf(tB1[1] + bB1, 0.f);
        tB2[0] = fmaxf(tB2[0] + bB0, 0.f); tB2[1] = fmaxf(tB2[1] + bB1, 0.f);
        tB3[0] = fmaxf(tB3[0] + bB0, 0.f); tB3[1] = fmaxf(tB3[1] + bB1, 0.f);
    }
    float* op = part + (size_t)pslot * 256 * S;
    {
        int sp = s0 + xg * 4;
        size_t rA0 = (size_t)c0 * S + sp;
        size_t rA1 = rA0 + S;
        if (sp + 0 < S) { op[rA0 + 0] = tA0[0]; op[rA1 + 0] = tA0[1]; }
        if (sp + 1 < S) { op[rA0 + 1] = tA1[0]; op[rA1 + 1] = tA1[1]; }
        if (sp + 2 < S) { op[rA0 + 2] = tA2[0]; op[rA1 + 2] = tA2[1]; }
        if (sp + 3 < S) { op[rA0 + 3] = tA3[0]; op[rA1 + 3] = tA3[1]; }
        size_t rB0 = rA0 + (size_t)64 * S;
        size_t rB1 = rB0 + S;
        if (sp + 0 < S) { op[rB0 + 0] = tB0[0]; op[rB1 + 0] = tB0[1]; }
        if (sp + 1 < S) { op[rB0 + 1] = tB1[0]; op[rB1 + 1] = tB1[1]; }
        if (sp + 2 < S) { op[rB0 + 2] = tB2[0]; op[rB1 + 2] = tB2[1]; }
        if (sp + 3 < S) { op[rB0 + 3] = tB3[0]; op[rB1 + 3] = tB3[1]; }
    }
}

// ---------------------------------------------------------------- fused 1x1 heads (+ inline finalize for npan=8 levels)
// For levels 2-4, v is recomputed with finalize's exact op order:
// ((p0+p1+...+p7) + bias, fmax 0) — identical bits.
struct HeadMap {
    const float* h[5];
    int S[5], abase[5], npan[5], bstart[6];
};

__global__ __launch_bounds__(256) void head_all(
    HeadMap hm, const float* __restrict__ wc,
    const float* __restrict__ bc, const float* __restrict__ wr,
    const float* __restrict__ br, const float* __restrict__ bias,
    float* __restrict__ cls_out, float* __restrict__ reg_out)
{
#pragma clang fp contract(off)
    int bid = blockIdx.x;
    int l = (bid >= hm.bstart[1]) + (bid >= hm.bstart[2]) +
            (bid >= hm.bstart[3]) + (bid >= hm.bstart[4]);
    int local = bid - hm.bstart[l];
    const float* __restrict__ h = hm.h[l];
    const int S = hm.S[l];
    const int abase = hm.abase[l];
    const int npan = hm.npan[l];
    int s = local * 256 + threadIdx.x;
    if (s >= S) return;
    float ac[6]  = {0.f};
    float ar[12] = {0.f};
    for (int c = 0; c < 256; ++c) {
        size_t i = (size_t)c * S + s;
        float v;
        if (npan == 1) {
            v = h[i];
        } else {
            float vv = h[i];
            for (int p = 1; p < 8; ++p)
                vv = vv + h[(size_t)p * 256 * S + i];   // strict panel order
            v = fmaxf(vv + bias[c], 0.f);
        }
#pragma unroll
        for (int ch = 0; ch < 6; ++ch) {
            float prod = wc[ch * 256 + c] * v;
            ac[ch] = ac[ch] + prod;
        }
#pragma unroll
        for (int ch = 0; ch < 12; ++ch) {
            float prod = wr[ch * 256 + c] * v;
            ar[ch] = ar[ch] + prod;
        }
    }
    long b2 = (long)abase + (long)s * 3;
#pragma unroll
    for (int a = 0; a < 3; ++a) {
#pragma unroll
        for (int c2 = 0; c2 < 2; ++c2)
            cls_out[(b2 + a) * 2 + c2] = ac[a * 2 + c2] + bc[a * 2 + c2];
#pragma unroll
        for (int d = 0; d < 4; ++d)
            reg_out[(b2 + a) * 4 + d] = ar[a * 4 + d] + br[a * 4 + d];
    }
}

// ---------------------------------------------------------------- f32 score + key + hist (+ anchors inline, bit-identical)
__global__ __launch_bounds__(256) void score_k(
    const float* __restrict__ cls, const float* __restrict__ reg,
    BaseTab bt, u64* __restrict__ keys, u32* __restrict__ hist,
    float* __restrict__ anc_out)
{
#pragma clang fp contract(off)
    int i = blockIdx.x * 256 + threadIdx.x;
    if (i >= A_TOT) return;
    // ---- anchor (same expressions as the old anchors_k)
    int l, base, gw, str;
    if (i < 120000)      { l = 0; base = 0;      gw = 200; str = 4;  }
    else if (i < 150000) { l = 1; base = 120000; gw = 100; str = 8;  }
    else if (i < 157500) { l = 2; base = 150000; gw = 50;  str = 16; }
    else if (i < 159375) { l = 3; base = 157500; gw = 25;  str = 32; }
    else                 { l = 4; base = 159375; gw = 13;  str = 61; }
    int j = i - base;
    int sj = j / 3;
    int a = j - sj * 3;
    int yy = sj / gw;
    int xx = sj - yy * gw;
    float sx = (float)(xx * str), sy = (float)(yy * str);
    const float* bb = &bt.v[(l * 3 + a) * 4];
    float a0 = (sx + bb[0]) / 800.0f;
    float a1 = (sy + bb[1]) / 800.0f;
    float a2 = (sx + bb[2]) / 800.0f;
    float a3 = (sy + bb[3]) / 800.0f;
    anc_out[4 * i + 0] = a0;
    anc_out[4 * i + 1] = a1;
    anc_out[4 * i + 2] = a2;
    anc_out[4 * i + 3] = a3;
    // ---- softmax score
    float l0 = cls[2 * i], l1 = cls[2 * i + 1];
    float m  = fmaxf(l0, l1);
    float e0 = pexp_f(l0 - m);
    float e1 = pexp_f(l1 - m);
    float sum = e0 + e1;
    float sc  = e1 / sum;
    // ---- validity (decode chain, same op order; only valid used)
    float acx = (a2 + a0) / 2.0f, acy = (a3 + a1) / 2.0f;
    float aw = a2 - a0, ah = a3 - a1;
    float t0 = reg[4 * i], t1 = reg[4 * i + 1], t2 = reg[4 * i + 2], t3 = reg[4 * i + 3];
    float cx = (t0 * aw) + acx;
    float cy = (t1 * ah) + acy;
    float w  = pexp_f(t2) * aw;
    float hh = pexp_f(t3) * ah;
    float bx1 = fminf(fmaxf(cx - w / 2.0f, 0.f), 1.f);
    float by1 = fminf(fmaxf(cy - hh / 2.0f, 0.f), 1.f);
    float bx2 = fminf(fmaxf(cx + w / 2.0f, 0.f), 1.f);
    float by2 = fminf(fmaxf(cy + hh / 2.0f, 0.f), 1.f);
    float wsz = bx2 - bx1, hsz = by2 - by1;
    bool valid = (hsz >= 0.01f) && (wsz >= 0.01f);

    float score = valid ? sc : -INFINITY;
    u32 u = mono32f(score);
    keys[i] = ((u64)u << 32) | (u32)(~(u32)i);   // desc score, asc index
    atomicAdd(&hist[u >> 15], 1u);
}

// ---------------------------------------------------------------- coarse threshold bin
__global__ __launch_bounds__(1024) void topk_thresh(const u32* __restrict__ hist,
                                                    u32* __restrict__ counters) {
    __shared__ u32 part[1024];
    int t = threadIdx.x;
    u32 s = 0;
    for (int q = 0; q < 128; ++q) s += hist[HIST_BINS - 1 - (t * 128 + q)];
    part[t] = s;
    __syncthreads();
    if (t == 0) {
        u32 cum = 0, cumBefore = 0;
        int tc = 1023;
        for (int c = 0; c < 1024; ++c) {
            if (cum + part[c] >= PRE_NMS) { tc = c; cumBefore = cum; break; }
            cum += part[c];
        }
        u32 cum2 = cumBefore;
        int bstar = 0;
        for (int q = 0; q < 128; ++q) {
            int b = HIST_BINS - 1 - (tc * 128 + q);
            u32 hv = hist[b];
            if (cum2 + hv >= PRE_NMS) { bstar = b; break; }
            cum2 += hv;
        }
        counters[0] = (u32)bstar;
        counters[1] = cum2;
    }
}

// ---------------------------------------------------------------- fine histogram in bstar bin
__global__ __launch_bounds__(256) void hist2_k(const u64* __restrict__ keys,
                                               const u32* __restrict__ counters,
                                               u32* __restrict__ hist2) {
    int i = blockIdx.x * 256 + threadIdx.x;
    if (i >= A_TOT) return;
    u32 u = (u32)(keys[i] >> 32);
    if ((u >> 15) == counters[0]) atomicAdd(&hist2[u & 0x7FFF], 1u);
}

// ---------------------------------------------------------------- exact 32-bit cutoff
__global__ __launch_bounds__(1024) void thresh2_k(const u32* __restrict__ hist2,
                                                  u32* __restrict__ counters) {
    __shared__ u32 part[1024];
    int t = threadIdx.x;
    u32 s = 0;
    for (int q = 0; q < 32; ++q) s += hist2[HIST2_BINS - 1 - (t * 32 + q)];
    part[t] = s;
    __syncthreads();
    if (t == 0) {
        u32 bstar = counters[0];
        u32 cum = counters[1];
        int tc = 1023;
        u32 cumBefore = cum;
        for (int c = 0; c < 1024; ++c) {
            if (cum + part[c] >= PRE_NMS) { tc = c; cumBefore = cum; break; }
            cum += part[c];
        }
        u32 cum2 = cumBefore;
        u32 low = 0;
        for (int q = 0; q < 32; ++q) {
            int b = HIST2_BINS - 1 - (tc * 32 + q);
            u32 hv = hist2[b];
            if (cum2 + hv >= PRE_NMS) { low = (u32)b; break; }
            cum2 += hv;
        }
        counters[3] = (bstar << 15) | low;   // exact monotone-u cutoff
    }
}

// ---------------------------------------------------------------- compact survivors (exact)
__global__ __launch_bounds__(256) void compact_k(const u64* __restrict__ keys,
                                                 u32* __restrict__ counters,
                                                 u64* __restrict__ surv) {
    int i = blockIdx.x * 256 + threadIdx.x;
    if (i >= A_TOT) return;
    u32 cut = counters[3];
    u64 k = keys[i];
    if ((u32)(k >> 32) >= cut) {
        u32 slot = atomicAdd(&counters[2], 1u);
        if (slot < SURV_CAP) surv[slot] = k;
    }
}

// ---------------------------------------------------------------- bitonic sort + gather (recompute decode)
// Adaptive size: if n <= 4096 sort 4096 (78 passes) else 8192 (91). Zeros sort
// to the back either way; first PRE_NMS entries identical -> bit-exact.
__global__ __launch_bounds__(1024) void sort_topk(
    const u64* __restrict__ surv, const u32* __restrict__ counters,
    const float* __restrict__ reg, const float* __restrict__ anc,
    float* __restrict__ boxes4k, u64* __restrict__ finmask)
{
    __shared__ u64 K[SURV_CAP];   // 64 KB
    int t = threadIdx.x;
    u32 n = counters[2];
    if (n > SURV_CAP) n = SURV_CAP;
    const int msize = (n <= 4096) ? 4096 : SURV_CAP;
    for (int p = t; p < msize; p += 1024) K[p] = (p < (int)n) ? surv[p] : 0ull;
    __syncthreads();
    for (int k = 2; k <= msize; k <<= 1) {
        for (int j = k >> 1; j > 0; j >>= 1) {
            for (int p = t; p < msize / 2; p += 1024) {
                int i = 2 * p - (p & (j - 1));
                int pr = i + j;
                bool desc = ((i & k) == 0);
                u64 a = K[i], b = K[pr];
                if (desc ? (a < b) : (a > b)) { K[i] = b; K[pr] = a; }
            }
            __syncthreads();
        }
    }
    for (int jj = t; jj < PRE_NMS; jj += 1024) {
        u64 key = K[jj];
        u32 u = (u32)(key >> 32);
        float b0 = 0.f, b1 = 0.f, b2 = 0.f, b3 = 0.f;
        if (u > MONO_NEG_INF) {
            u32 idx = ~(u32)key;
            bool valid;
            float4 bx = decode_box(reg, anc, idx, &valid);
            b0 = bx.x; b1 = bx.y; b2 = bx.z; b3 = bx.w;
        }
        boxes4k[4 * jj + 0] = b0;
        boxes4k[4 * jj + 1] = b1;
        boxes4k[4 * jj + 2] = b2;
        boxes4k[4 * jj + 3] = b3;
    }
    if (t < NWORDS) {
        u64 wmask = 0;
        for (int b = 0; b < 64; ++b) {
            int jj = t * 64 + b;
            if (jj < PRE_NMS) {
                u32 u = (u32)(K[jj] >> 32);
                if (u > MONO_NEG_INF) wmask |= (1ull << b);
            }
        }
        finmask[t] = wmask;
    }
}

// ---------------------------------------------------------------- suppression matrix (f32, np op order)
__global__ __launch_bounds__(64) void supmat_k(const float* __restrict__ boxes4k,
                                               u64* __restrict__ sup) {
#pragma clang fp contract(off)
    __shared__ float cb[64][4];
    int rb = blockIdx.y, cbk = blockIdx.x;
    int tl = threadIdx.x;
    int j = cbk * 64 + tl;
    if (j < PRE_NMS) {
        cb[tl][0] = boxes4k[4 * j + 0];
        cb[tl][1] = boxes4k[4 * j + 1];
        cb[tl][2] = boxes4k[4 * j + 2];
        cb[tl][3] = boxes4k[4 * j + 3];
    } else {
        cb[tl][0] = cb[tl][1] = cb[tl][2] = cb[tl][3] = 0.f;
    }
    __syncthreads();
    int i = rb * 64 + tl;
    if (i >= PRE_NMS) return;
    float ax1 = boxes4k[4 * i + 0], ay1 = boxes4k[4 * i + 1];
    float ax2 = boxes4k[4 * i + 2], ay2 = boxes4k[4 * i + 3];
    float aarea = fmaxf(ax2 - ax1, 0.f) * fmaxf(ay2 - ay1, 0.f);
    u64 w = 0;
    for (int q = 0; q < 64; ++q) {
        int jg = cbk * 64 + q;
        if (jg >= PRE_NMS || jg <= i) continue;
        float bx1 = cb[q][0], by1 = cb[q][1], bx2 = cb[q][2], by2 = cb[q][3];
        float barea = fmaxf(bx2 - bx1, 0.f) * fmaxf(by2 - by1, 0.f);
        float lx = fmaxf(ax1, bx1), ly = fmaxf(ay1, by1);
        float rx = fminf(ax2, bx2), ry = fminf(ay2, by2);
        float iw = fmaxf(rx - lx, 0.f), ih = fmaxf(ry - ly, 0.f);
        float inter = iw * ih;
        float uni = (aarea + barea) - inter;
        float iou = (uni > 0.f) ? inter / uni : 0.f;
        if (iou > 0.7f) w |= (1ull << q);
    }
    sup[(size_t)i * NWORDS + cbk] = w;
}

// ---------------------------------------------------------------- sequential NMS scan + output (merged, depth-3 prefetch)
__device__ inline u64 shfl_u64(u64 v, int lane) {
    int lo = __shfl((int)(u32)(v & 0xFFFFFFFFull), lane, 64);
    int hi = __shfl((int)(u32)(v >> 32), lane, 64);
    return ((u64)(u32)hi << 32) | (u32)lo;
}

__global__ __launch_bounds__(256) void nms_out_k(const u64* __restrict__ sup,
                                                 const u64* __restrict__ finmask,
                                                 const float* __restrict__ boxes4k,
                                                 float* __restrict__ roi_out) {
    __shared__ u64 keepw_s[NWORDS];
    __shared__ u32 pref[NWORDS + 1];
    int t = threadIdx.x;
    if (t < 64) {
        int lane = t;
        u64 keep = (lane < NWORDS) ? finmask[lane] : 0ull;
        u64 cur[8], n1[8], n2[8], nw[8];
#define LDROW(dst_, i0_)                                                       \
        _Pragma("unroll")                                                      \
        for (int q = 0; q < 8; ++q) {                                          \
            int i_ = (i0_) + q;                                                \
            dst_[q] = (lane < NWORDS && i_ < PRE_NMS)                          \
                      ? sup[(size_t)i_ * NWORDS + lane] : 0ull;                \
        }
        LDROW(cur, 0)
        LDROW(n1, 8)
        LDROW(n2, 16)
        for (int base = 0; base < PRE_NMS; base += 8) {
            LDROW(nw, base + 24)          // 24 rows in flight over this body
#pragma unroll
            for (int q = 0; q < 8; ++q) {
                int i = base + q;
                int wi = i >> 6, bi = i & 63;
                u64 kw = shfl_u64(keep, wi);
                if ((kw >> bi) & 1ull) keep &= ~cur[q];
            }
#pragma unroll
            for (int q = 0; q < 8; ++q) { cur[q] = n1[q]; n1[q] = n2[q]; n2[q] = nw[q]; }
        }
#undef LDROW
        if (lane < NWORDS) keepw_s[lane] = keep;
    }
    __syncthreads();
    if (t == 0) {
        u32 run = 0;
        for (int w = 0; w < NWORDS; ++w) { pref[w] = run; run += (u32)__popcll(keepw_s[w]); }
        pref[NWORDS] = run;
    }
    __syncthreads();
    u32 total = pref[NWORDS];
    u32 nk = total < (u32)POST_NMS ? total : (u32)POST_NMS;
    for (int j = t; j < PRE_NMS; j += 256) {
        int wi = j >> 6, bi = j & 63;
        u64 kw = keepw_s[wi];
        if ((kw >> bi) & 1ull) {
            u32 rank = pref[wi] + (u32)__popcll(kw & ((1ull << bi) - 1ull));
            if (rank < (u32)POST_NMS) {
                roi_out[4 * rank + 0] = boxes4k[4 * j + 0];
                roi_out[4 * rank + 1] = boxes4k[4 * j + 1];
                roi_out[4 * rank + 2] = boxes4k[4 * j + 2];
                roi_out[4 * rank + 3] = boxes4k[4 * j + 3];
            }
        }
    }
    for (int r2 = t; r2 < POST_NMS; r2 += 256) {
        if ((u32)r2 >= nk) {
            roi_out[4 * r2 + 0] = 0.f;
            roi_out[4 * r2 + 1] = 0.f;
            roi_out[4 * r2 + 2] = 0.f;
            roi_out[4 * r2 + 3] = 0.f;
        }
    }
}

// ================================================================ host
extern "C" void kernel_launch(void* const* d_in, const int* in_sizes, int n_in,
                              void* d_out, int out_size, void* d_ws, size_t ws_size,
                              hipStream_t stream) {
    const float* feat[5] = {
        (const float*)d_in[1], (const float*)d_in[2], (const float*)d_in[3],
        (const float*)d_in[4], (const float*)d_in[5]};
    const float* w_inter = (const float*)d_in[6];
    const float* b_inter = (const float*)d_in[7];
    const float* w_cls   = (const float*)d_in[8];
    const float* b_cls   = (const float*)d_in[9];
    const float* w_reg   = (const float*)d_in[10];
    const float* b_reg   = (const float*)d_in[11];

    float* out     = (float*)d_out;
    float* out_cls = out;                       // 159882*2
    float* out_reg = out + 319764;              // 159882*4
    float* out_roi = out + 959292;              // 1000*4
    float* out_anc = out + 963292;              // 159882*4

    static const int GH[5]    = {200, 100, 50, 25, 13};
    static const int GW[5]    = {200, 100, 50, 25, 13};
    static const int SL[5]    = {40000, 10000, 2500, 625, 169};
    static const int ABASE[5] = {0, 120000, 150000, 157500, 159375};
    static const int NPAN_ST[5] = {1, 1, 8, 8, 8};   // panel-partial slots stored

    // ---- workspace carve (~85 MB total)
    char* p = (char*)d_ws;
    size_t off = 0;
    auto alloc = [&](size_t bytes) -> void* {
        void* r = p + off;
        off = (off + bytes + 255) & ~(size_t)255;
        return r;
    };
    float* Wt      = (float*)alloc((size_t)2304 * 256 * 4);
    float* part[5];
    for (int l = 0; l < 5; ++l)
        part[l] = (float*)alloc((size_t)NPAN_ST[l] * 256 * SL[l] * 4);
    u64*   keys    = (u64*)  alloc((size_t)A_TOT * 8);
    u32*   hist    = (u32*)  alloc((size_t)HIST_BINS * 4);
    u32*   hist2   = (u32*)  alloc((size_t)HIST2_BINS * 4);
    u32*   counters= (u32*)  alloc(256);
    u64*   surv    = (u64*)  alloc((size_t)SURV_CAP * 8);
    float* boxes4k = (float*)alloc((size_t)PRE_NMS * 4 * 4);
    u64*   finmask = (u64*)  alloc(64 * 8);
    u64*   supmat  = (u64*)  alloc((size_t)PRE_NMS * NWORDS * 8);
    (void)ws_size;

    // ---- host anchor base table, float32 to match np (round half-even)
    BaseTab bt;
    {
        const float sizes[5] = {32.f, 64.f, 128.f, 256.f, 512.f};
        const float asp[3] = {0.5f, 1.0f, 2.0f};
        for (int l = 0; l < 5; ++l)
            for (int a = 0; a < 3; ++a) {
                float hr = sqrtf(asp[a]);
                float wr = 1.0f / hr;
                float wsf = sizes[l] * wr;
                float hsf = sizes[l] * hr;
                bt.v[(l * 3 + a) * 4 + 0] = rintf(-wsf / 2.0f);
                bt.v[(l * 3 + a) * 4 + 1] = rintf(-hsf / 2.0f);
                bt.v[(l * 3 + a) * 4 + 2] = rintf( wsf / 2.0f);
                bt.v[(l * 3 + a) * 4 + 3] = rintf( hsf / 2.0f);
            }
    }

    wt_k<<<2304, 256, 0, stream>>>(w_inter, Wt, hist, hist2, counters);

    // ---- fused conv (all 5 levels, one launch, linear-position tiles)
    ConvMap cm;
    cm.Wt = Wt;
    cm.bias = b_inter;
    int bacc = 0;
    for (int l = 0; l < 5; ++l) {
        cm.feat[l] = feat[l];
        cm.part[l] = part[l];
        int st = (SL[l] + 31) / 32;
        cm.st[l] = st; cm.gh[l] = GH[l]; cm.gw[l] = GW[l]; cm.S[l] = SL[l];
        cm.M[l] = (((u64)1 << 48) + (u64)GW[l] - 1) / (u64)GW[l];
        int zsplit = NPAN_ST[l];
        cm.npan[l] = (zsplit == 1) ? 8 : 1;
        cm.fuse[l] = (zsplit == 1) ? 1 : 0;       // bias+relu fused for levels 0/1
        cm.bstart[l] = bacc;
        bacc += st * (zsplit * 2);
    }
    cm.bstart[5] = bacc;
    conv_all<<<bacc, 256, 0, stream>>>(cm);

    // ---- fused heads (finalize for levels 2-4 done inline)
    HeadMap hm;
    int hacc = 0;
    for (int l = 0; l < 5; ++l) {
        hm.h[l] = part[l];
        hm.S[l] = SL[l];
        hm.abase[l] = ABASE[l];
        hm.npan[l] = NPAN_ST[l];
        hm.bstart[l] = hacc;
        hacc += (SL[l] + 255) / 256;
    }
    hm.bstart[5] = hacc;
    head_all<<<hacc, 256, 0, stream>>>(hm, w_cls, b_cls, w_reg, b_reg,
                                       b_inter, out_cls, out_reg);

    int nbA = (A_TOT + 255) / 256;
    score_k<<<nbA, 256, 0, stream>>>(out_cls, out_reg, bt, keys, hist, out_anc);
    topk_thresh<<<1, 1024, 0, stream>>>(hist, counters);
    hist2_k<<<nbA, 256, 0, stream>>>(keys, counters, hist2);
    thresh2_k<<<1, 1024, 0, stream>>>(hist2, counters);
    compact_k<<<nbA, 256, 0, stream>>>(keys, counters, surv);
    sort_topk<<<1, 1024, 0, stream>>>(surv, counters, out_reg, out_anc, boxes4k, finmask);
    supmat_k<<<dim3(NWORDS, NWORDS), 64, 0, stream>>>(boxes4k, supmat);
    nms_out_k<<<1, 256, 0, stream>>>(supmat, finmask, boxes4k, out_roi);
}